// Round 15
// baseline (88.643 us; speedup 1.0000x reference)
//
#include <hip/hip_runtime.h>
#include <hip/hip_bf16.h>
#include <math.h>

#define BB   16
#define NN   96
#define DD   128
#define NCLS 10
#define NTOK 14

typedef __attribute__((ext_vector_type(8))) short bf16x8;
typedef __attribute__((ext_vector_type(8))) unsigned short u16x8;
typedef __attribute__((ext_vector_type(4))) float f32x4;

__device__ __forceinline__ float scalar_as_float(int v) {
    if (v >= -1000000 && v <= 1000000) return (float)v;
    return __int_as_float(v);
}
__device__ __forceinline__ unsigned short f2bf(float f) {
    unsigned u = __float_as_uint(f);
    return (unsigned short)((u + 0x7FFFu + ((u >> 16) & 1u)) >> 16);
}
__device__ __forceinline__ float bf2f(unsigned short h) {
    return __uint_as_float(((unsigned)h) << 16);
}

#define MFMA(A, B, C) __builtin_amdgcn_mfma_f32_16x16x32_bf16(A, B, C, 0, 0, 0)

// ---- merged prep ----
// [0,196) Mtab(ti,tj) + t2tab | [196,212) AT | [212,220) W2 frag | [220,224) W1x bf16
// [224,228) Wo1 bf16 | [228] ctab = centroids @ bf16(W1x)
__global__ __launch_bounds__(256) void k_prep(
    const float* __restrict__ A, const float* __restrict__ embed_W,
    const float* __restrict__ W1, const float* __restrict__ b1,
    const float* __restrict__ W2, const float* __restrict__ b2,
    const float* __restrict__ Wo1,
    float* __restrict__ Mtab, float* __restrict__ t2tab, float* __restrict__ AT,
    unsigned short* __restrict__ w2hi, unsigned short* __restrict__ w1xb,
    unsigned short* __restrict__ wo1b, float* __restrict__ ctab)
{
    const int bx = blockIdx.x;
    const int t  = threadIdx.x;
    const float* W1x = W1 + DD * DD;

    if (bx < NTOK * NTOK) {        // Mtab(ti,tj): the only 196 distinct H rows in round 0
        const int ti = bx / NTOK, tj = bx % NTOK;
        const int d = t & 127, half = t >> 7;
        __shared__ float part[2][DD];
        __shared__ unsigned short hb[DD];
        {
            const float* erow  = embed_W + (half ? tj : ti) * DD;
            const float* wbase = half ? W1x : W1;
            float acc = 0.f;
#pragma unroll 8
            for (int k = 0; k < DD; ++k)
                acc = fmaf(erow[k], wbase[k * DD + d], acc);
            part[half][d] = acc;
        }
        __syncthreads();
        if (half == 0) {
            const float v = part[0][d] + b1[d];
            if (tj == 0) t2tab[ti * DD + d] = v;
            hb[d] = f2bf(fmaxf(v + part[1][d], 0.f));
        }
        __syncthreads();
        {
            float m = 0.f;
#pragma unroll 8
            for (int kk = 0; kk < 64; ++kk) {
                const int k = half * 64 + kk;
                m = fmaf(bf2f(hb[k]), bf2f(f2bf(W2[k * DD + d])), m);
            }
            part[half][d] = m;
        }
        __syncthreads();
        if (half == 0)
            Mtab[(ti * NTOK + tj) * DD + d] = fmaxf(part[0][d] + part[1][d] + b2[d], 0.f);
    } else if (bx < 212) {         // A transpose
        const int b = bx - 196;
        __shared__ float tile[NN][NN + 1];
        for (int idx = t; idx < NN * NN; idx += 256)
            tile[idx / NN][idx % NN] = A[b * NN * NN + idx];
        __syncthreads();
        for (int idx = t; idx < NN * NN; idx += 256) {
            const int i = idx / NN, j = idx % NN;
            AT[b * NN * NN + idx] = tile[j][i];
        }
    } else if (bx < 220) {         // W2 -> MFMA B-frag layout, bf16
        const int dt = bx - 212;
        const int kc = t >> 6, ll = t & 63;
        const int base = ((dt * 4 + kc) * 64 + ll) * 8;
        const int c = dt * 16 + (ll & 15);
#pragma unroll
        for (int e = 0; e < 8; ++e)
            w2hi[base + e] = f2bf(W2[(kc * 32 + (ll >> 4) * 8 + e) * DD + c]);
    } else if (bx < 224) {         // W1x -> bf16
        const int base = (bx - 220) * 4096 + t * 16;
#pragma unroll
        for (int e = 0; e < 16; ++e) w1xb[base + e] = f2bf(W1x[base + e]);
    } else if (bx < 228) {         // Wo1 -> bf16
        const int base = (bx - 224) * 4096 + t * 16;
#pragma unroll
        for (int e = 0; e < 16; ++e) wo1b[base + e] = f2bf(Wo1[base + e]);
    } else {                       // ctab[c][h] = sum_k centroids[c][k] * bf16(W1x[k][h])
        const int h = t & 127, half = t >> 7;
        __shared__ float cpart[2][NCLS][DD];
#pragma unroll
        for (int c = 0; c < NCLS; ++c) {
            float acc = 0.f;
#pragma unroll 8
            for (int kk = 0; kk < 64; ++kk) {
                const int k = half * 64 + kk;
                acc = fmaf(embed_W[(4 + c) * DD + k], bf2f(f2bf(W1x[k * DD + h])), acc);
            }
            cpart[half][c][h] = acc;
        }
        __syncthreads();
        if (half == 0) {
#pragma unroll
            for (int c = 0; c < NCLS; ++c)
                ctab[c * DD + h] = cpart[0][c][h] + cpart[1][c][h];
        }
    }
}

// -------- round 0 fast path: agg = A-weighted gather-sum over Mtab --------
__global__ __launch_bounds__(512, 4) void k_round0(
    const int* __restrict__ tok, const float* __restrict__ AT,
    const float* __restrict__ Mtab, const float* __restrict__ embed_W,
    const unsigned short* __restrict__ wo1b, const float* __restrict__ bo1,
    const float* __restrict__ Wo2, const unsigned short* __restrict__ w1xb,
    const float* __restrict__ ctab, const int* __restrict__ tau_p,
    float* __restrict__ x, unsigned short* __restrict__ xj_out)
{
    const int bx = blockIdx.x;
    const int b  = bx >> 5;
    const int is = bx & 31;
    const int t  = threadIdx.x;
    const int w  = t >> 6;
    const int l  = t & 63;
    const int row0 = b * NN + is;

    __shared__ __align__(16) float mt[3][NTOK * DD];
    __shared__ float at3[3][NN];
    __shared__ int   tkj[NN];
    __shared__ float agg_s[3][DD];
    __shared__ float xn_s[3][DD];
    __shared__ float ph_s[4][3][DD];
    __shared__ float pj_s[4][3][DD];

    const int ti0 = tok[row0], ti1 = tok[row0 + 32], ti2 = tok[row0 + 64];
    if (t < NN) {
        tkj[t]    = tok[b * NN + t];
        at3[0][t] = AT[row0 * NN + t];
        at3[1][t] = AT[(row0 + 32) * NN + t];
        at3[2][t] = AT[(row0 + 64) * NN + t];
    }
    for (int idx = t; idx < 3 * NTOK * DD; idx += 512) {
        const int u = idx / (NTOK * DD), rd = idx - u * (NTOK * DD);
        const int tiu = (u == 0) ? ti0 : ((u == 1) ? ti1 : ti2);
        mt[u][rd] = Mtab[tiu * NTOK * DD + rd];
    }
    __syncthreads();

    if (t < 192) {
        const int u = t >> 6, d2 = t & 63;
        const float2* mtu = (const float2*)mt[u];
        float2 acc = {0.f, 0.f};
#pragma unroll 4
        for (int j = 0; j < NN; ++j) {
            const float a = at3[u][j];
            const float2 m = mtu[tkj[j] * 64 + d2];
            acc.x = fmaf(a, m.x, acc.x);
            acc.y = fmaf(a, m.y, acc.y);
        }
        *(float2*)&agg_s[u][d2 * 2] = acc;
    }
    __syncthreads();

    float xr0 = 0.f, xr1 = 0.f;
    if (w < 3) {
        const int tk = (w == 0) ? ti0 : ((w == 1) ? ti1 : ti2);
        xr0 = embed_W[tk * DD + l]      + agg_s[w][l];
        xr1 = embed_W[tk * DD + l + 64] + agg_s[w][l + 64];
        xn_s[w][l]      = xr0;
        xn_s[w][l + 64] = xr1;
    }
    __syncthreads();

    {   // fused dual matvec: hid partials (Wo1 bf16) + xj-base partials (W1x bf16)
        const int q = t >> 7, h = t & 127;
        float h0 = 0.f, h1 = 0.f, h2 = 0.f, j0 = 0.f, j1 = 0.f, j2 = 0.f;
#pragma unroll
        for (int kk = 0; kk < 32; ++kk) {
            const int k = q * 32 + kk;
            const float wo = bf2f(wo1b[k * DD + h]);
            const float wx = bf2f(w1xb[k * DD + h]);
            const float x0 = xn_s[0][k], x1 = xn_s[1][k], x2 = xn_s[2][k];
            h0 = fmaf(x0, wo, h0); h1 = fmaf(x1, wo, h1); h2 = fmaf(x2, wo, h2);
            j0 = fmaf(x0, wx, j0); j1 = fmaf(x1, wx, j1); j2 = fmaf(x2, wx, j2);
        }
        ph_s[q][0][h] = h0; ph_s[q][1][h] = h1; ph_s[q][2][h] = h2;
        pj_s[q][0][h] = j0; pj_s[q][1][h] = j1; pj_s[q][2][h] = j2;
    }
    __syncthreads();

    if (w < 3) {
        const int row_u = row0 + 32 * w;
        const float hid0 = fmaxf(ph_s[0][w][l] + ph_s[1][w][l]
                               + ph_s[2][w][l] + ph_s[3][w][l] + bo1[l], 0.f);
        const float hid1 = fmaxf(ph_s[0][w][l + 64] + ph_s[1][w][l + 64]
                               + ph_s[2][w][l + 64] + ph_s[3][w][l + 64] + bo1[l + 64], 0.f);
        float lgp[NCLS];
#pragma unroll
        for (int c = 0; c < NCLS; ++c)
            lgp[c] = hid0 * Wo2[l * NCLS + c] + hid1 * Wo2[(l + 64) * NCLS + c];
#pragma unroll
        for (int s = 1; s < 64; s <<= 1) {
#pragma unroll
            for (int c = 0; c < NCLS; ++c) lgp[c] += __shfl_xor(lgp[c], s);
        }
        float mx = -1e30f;
#pragma unroll
        for (int c = 0; c < NCLS; ++c) mx = fmaxf(mx, lgp[c]);
        const float inv_tau = 1.f / scalar_as_float(tau_p[0]);
        float p[NCLS], den = 0.f;
#pragma unroll
        for (int c = 0; c < NCLS; ++c) { p[c] = expf((lgp[c] - mx) * inv_tau); den += p[c]; }
        const float invden = 1.f / den;
        float xj0 = pj_s[0][w][l] + pj_s[1][w][l] + pj_s[2][w][l] + pj_s[3][w][l];
        float xj1 = pj_s[0][w][l + 64] + pj_s[1][w][l + 64]
                  + pj_s[2][w][l + 64] + pj_s[3][w][l + 64];
#pragma unroll
        for (int c = 0; c < NCLS; ++c) {
            const float pc = p[c] * invden;
            xr0 = fmaf(pc, embed_W[(4 + c) * DD + l], xr0);
            xr1 = fmaf(pc, embed_W[(4 + c) * DD + l + 64], xr1);
            xj0 = fmaf(pc, ctab[c * DD + l], xj0);
            xj1 = fmaf(pc, ctab[c * DD + l + 64], xj1);
        }
        x[row_u * DD + l]      = xr0;
        x[row_u * DD + l + 64] = xr1;
        xj_out[row_u * DD + l]      = f2bf(xj0);
        xj_out[row_u * DD + l + 64] = f2bf(xj1);
    }
}

// -------- rounds 1..4: pipelined MFMA GEMM (R13 STAGE: loads in-loop, short liveness)
// + fused dual-matvec epilogue (ctab linearity kills the P5/P6 xj phase) --------
template<int FIN>
__global__ __launch_bounds__(512, 4) void k_round(
    const int* __restrict__ tok, const float* __restrict__ AT,
    const float* __restrict__ t2tab,
    const unsigned short* __restrict__ xj_in,
    const unsigned short* __restrict__ w2hi, const float* __restrict__ b2,
    const float* __restrict__ Wo1, const unsigned short* __restrict__ wo1b,
    const float* __restrict__ bo1, const float* __restrict__ Wo2,
    const float* __restrict__ embed_W, const unsigned short* __restrict__ w1xb,
    const float* __restrict__ ctab, const int* __restrict__ tau_p,
    float* __restrict__ x, unsigned short* __restrict__ xj_out,
    float* __restrict__ out, float* __restrict__ x_all)
{
    const int bx = blockIdx.x;
    const int b  = bx >> 5;
    const int is = bx & 31;
    const int t  = threadIdx.x;
    const int w  = t >> 6;
    const int l  = t & 63;
    const int jg  = w >> 2;
    const int dg  = w & 3;
    const int jg3 = jg * 3;
    const int d0 = (t & 15) * 8;
    const int row0 = b * NN + is;

    __shared__ __align__(16) unsigned short hs[2][NN * DD];
    __shared__ float ac_s[2][NN];
    __shared__ float agg_part[3][2][DD];
    __shared__ float xn_s[3][DD];
    __shared__ float ph_s[4][3][DD];
    __shared__ float pj_s[4][3][DD];

    const int tk0 = tok[row0], tk1 = tok[row0 + 32], tk2 = tok[row0 + 64];

    const bf16x8* WH = (const bf16x8*)w2hi;
    const int f0 = (dg * 4) * 64 + l;
    const int f1 = ((dg + 4) * 4) * 64 + l;
    bf16x8 bh00 = WH[f0],        bh10 = WH[f1];
    bf16x8 bh01 = WH[f0 + 64],   bh11 = WH[f1 + 64];
    bf16x8 bh02 = WH[f0 + 128],  bh12 = WH[f1 + 128];
    bf16x8 bh03 = WH[f0 + 192],  bh13 = WH[f1 + 192];
    asm volatile("" : "+v"(bh00), "+v"(bh01), "+v"(bh02), "+v"(bh03),
                      "+v"(bh10), "+v"(bh11), "+v"(bh12), "+v"(bh13));
    const float b2v0 = b2[dg * 16 + (l & 15)];
    const float b2v1 = b2[64 + dg * 16 + (l & 15)];
    const u16x8* xj8 = (const u16x8*)(xj_in + b * NN * DD);

    auto STAGE = [&](int u, int p) {
        const int row_u = row0 + 32 * u;
        const int tk = (u == 0) ? tk0 : ((u == 1) ? tk1 : tk2);
        const float4 ea = *(const float4*)(t2tab + tk * DD + d0);
        const float4 eb = *(const float4*)(t2tab + tk * DD + d0 + 4);
        float v8[8];
        v8[0] = ea.x; v8[1] = ea.y; v8[2] = ea.z; v8[3] = ea.w;
        v8[4] = eb.x; v8[5] = eb.y; v8[6] = eb.z; v8[7] = eb.w;
        if (t < NN) ac_s[p][t] = AT[row_u * NN + t];
#pragma unroll
        for (int it = 0; it < 3; ++it) {
            const int idx8 = t + it * 512;
            const int j = idx8 >> 4;
            const u16x8 xv = xj8[idx8];
            u16x8 hh;
#pragma unroll
            for (int e = 0; e < 8; ++e)
                hh[e] = f2bf(fmaxf(bf2f(xv[e]) + v8[e], 0.f));
            *(u16x8*)&hs[p][(j * DD + d0) ^ ((j & 7) << 3)] = hh;
        }
    };

    auto GEMM = [&](int u, int p) {
        float aggp0 = 0.f, aggp1 = 0.f;
        const unsigned short* hb = hs[p];
#pragma unroll
        for (int jj = 0; jj < 3; ++jj) {
            const int jt  = jg3 + jj;
            const int r16 = jt * 16 + (l & 15);
            const int ko  = (l >> 4) * 8;
            const int sw  = (r16 & 7) << 3;
            const bf16x8 a0 = *(const bf16x8*)&hb[(r16 * DD + ko     ) ^ sw];
            const bf16x8 a1 = *(const bf16x8*)&hb[(r16 * DD + ko + 32) ^ sw];
            const bf16x8 a2 = *(const bf16x8*)&hb[(r16 * DD + ko + 64) ^ sw];
            const bf16x8 a3 = *(const bf16x8*)&hb[(r16 * DD + ko + 96) ^ sw];
            f32x4 c0 = {0.f, 0.f, 0.f, 0.f}, c1 = {0.f, 0.f, 0.f, 0.f};
            c0 = MFMA(a0, bh00, c0);  c1 = MFMA(a0, bh10, c1);
            c0 = MFMA(a1, bh01, c0);  c1 = MFMA(a1, bh11, c1);
            c0 = MFMA(a2, bh02, c0);  c1 = MFMA(a2, bh12, c1);
            c0 = MFMA(a3, bh03, c0);  c1 = MFMA(a3, bh13, c1);
#pragma unroll
            for (int r = 0; r < 4; ++r) {
                const float a = ac_s[p][jt * 16 + (l >> 4) * 4 + r];
                aggp0 = fmaf(a, fmaxf(c0[r] + b2v0, 0.f), aggp0);
                aggp1 = fmaf(a, fmaxf(c1[r] + b2v1, 0.f), aggp1);
            }
        }
        aggp0 += __shfl_xor(aggp0, 16); aggp0 += __shfl_xor(aggp0, 32);
        aggp1 += __shfl_xor(aggp1, 16); aggp1 += __shfl_xor(aggp1, 32);
        if (l < 16) {
            agg_part[u][jg][dg * 16 + l]      = aggp0;
            agg_part[u][jg][64 + dg * 16 + l] = aggp1;
        }
    };

    STAGE(0, 0);
    __syncthreads();
    STAGE(1, 1);
    GEMM(0, 0);
    __syncthreads();
    STAGE(2, 0);
    GEMM(1, 1);
    __syncthreads();
    GEMM(2, 0);
    __syncthreads();

    // P1: x update
    float xr0 = 0.f, xr1 = 0.f;
    if (w < 3) {
        const int row_u = row0 + 32 * w;
        xr0 = x[row_u * DD + l]      + agg_part[w][0][l]      + agg_part[w][1][l];
        xr1 = x[row_u * DD + l + 64] + agg_part[w][0][l + 64] + agg_part[w][1][l + 64];
        xn_s[w][l]      = xr0;
        xn_s[w][l + 64] = xr1;
    }
    __syncthreads();

    // P2: fused dual matvec — hid partials + (if !FIN) xj-base partials
    {
        const int q = t >> 7, h = t & 127;
        float h0 = 0.f, h1 = 0.f, h2 = 0.f, j0 = 0.f, j1 = 0.f, j2 = 0.f;
#pragma unroll
        for (int kk = 0; kk < 32; ++kk) {
            const int k = q * 32 + kk;
            const float wo = FIN ? Wo1[k * DD + h] : bf2f(wo1b[k * DD + h]);
            const float x0 = xn_s[0][k], x1 = xn_s[1][k], x2 = xn_s[2][k];
            h0 = fmaf(x0, wo, h0); h1 = fmaf(x1, wo, h1); h2 = fmaf(x2, wo, h2);
            if (!FIN) {
                const float wx = bf2f(w1xb[k * DD + h]);
                j0 = fmaf(x0, wx, j0); j1 = fmaf(x1, wx, j1); j2 = fmaf(x2, wx, j2);
            }
        }
        ph_s[q][0][h] = h0; ph_s[q][1][h] = h1; ph_s[q][2][h] = h2;
        if (!FIN) { pj_s[q][0][h] = j0; pj_s[q][1][h] = j1; pj_s[q][2][h] = j2; }
    }
    __syncthreads();

    // P3: hid + logits + [FIN store | softmax + x + xj(ctab)]
    if (w < 3) {
        const int row_u = row0 + 32 * w;
        const float hid0 = fmaxf(ph_s[0][w][l] + ph_s[1][w][l]
                               + ph_s[2][w][l] + ph_s[3][w][l] + bo1[l], 0.f);
        const float hid1 = fmaxf(ph_s[0][w][l + 64] + ph_s[1][w][l + 64]
                               + ph_s[2][w][l + 64] + ph_s[3][w][l + 64] + bo1[l + 64], 0.f);
        float lgp[NCLS];
#pragma unroll
        for (int c = 0; c < NCLS; ++c)
            lgp[c] = hid0 * Wo2[l * NCLS + c] + hid1 * Wo2[(l + 64) * NCLS + c];
#pragma unroll
        for (int s = 1; s < 64; s <<= 1) {
#pragma unroll
            for (int c = 0; c < NCLS; ++c) lgp[c] += __shfl_xor(lgp[c], s);
        }
        if (FIN) {
#pragma unroll
            for (int c = 0; c < NCLS; ++c) {
                if (l == c) {
                    x_all[row_u * NCLS + c] = lgp[c];
                    if (is == 0 && w == 0) out[b * NCLS + c] = lgp[c];
                }
            }
        } else {
            float mx = -1e30f;
#pragma unroll
            for (int c = 0; c < NCLS; ++c) mx = fmaxf(mx, lgp[c]);
            const float inv_tau = 1.f / scalar_as_float(tau_p[0]);
            float p[NCLS], den = 0.f;
#pragma unroll
            for (int c = 0; c < NCLS; ++c) { p[c] = expf((lgp[c] - mx) * inv_tau); den += p[c]; }
            const float invden = 1.f / den;
            float xj0 = pj_s[0][w][l] + pj_s[1][w][l] + pj_s[2][w][l] + pj_s[3][w][l];
            float xj1 = pj_s[0][w][l + 64] + pj_s[1][w][l + 64]
                      + pj_s[2][w][l + 64] + pj_s[3][w][l + 64];
#pragma unroll
            for (int c = 0; c < NCLS; ++c) {
                const float pc = p[c] * invden;
                xr0 = fmaf(pc, embed_W[(4 + c) * DD + l], xr0);
                xr1 = fmaf(pc, embed_W[(4 + c) * DD + l + 64], xr1);
                xj0 = fmaf(pc, ctab[c * DD + l], xj0);
                xj1 = fmaf(pc, ctab[c * DD + l + 64], xj1);
            }
            x[row_u * DD + l]      = xr0;
            x[row_u * DD + l + 64] = xr1;
            xj_out[row_u * DD + l]      = f2bf(xj0);
            xj_out[row_u * DD + l + 64] = f2bf(xj1);
        }
    }
}

extern "C" void kernel_launch(void* const* d_in, const int* in_sizes, int n_in,
                              void* d_out, int out_size, void* d_ws, size_t ws_size,
                              hipStream_t stream)
{
    (void)in_sizes; (void)n_in; (void)out_size; (void)ws_size;
    const int*   tok     = (const int*)d_in[0];
    const float* Aab     = (const float*)d_in[1];
    const float* embed_W = (const float*)d_in[2];
    const float* W1      = (const float*)d_in[3];
    const float* b1      = (const float*)d_in[4];
    const float* W2      = (const float*)d_in[5];
    const float* b2      = (const float*)d_in[6];
    const float* Wo1     = (const float*)d_in[7];
    const float* bo1     = (const float*)d_in[8];
    const float* Wo2     = (const float*)d_in[9];
    const int*   tau_p   = (const int*)d_in[11];

    float* out   = (float*)d_out;
    float* x_all = out + BB * NCLS;

    float* ws     = (float*)d_ws;
    float* x      = ws;                                    // 196608 f
    float* ATr    = ws + BB * NN * DD;                     // 147456 f
    float* Mtab   = ATr + BB * NN * NN;                    // 25088 f
    float* t2tab  = Mtab + NTOK * NTOK * DD;               // 1792 f
    float* ctab   = t2tab + NTOK * DD;                     // 1280 f
    unsigned short* xjA  = (unsigned short*)(ctab + NCLS * DD);
    unsigned short* xjB  = xjA + BB * NN * DD;             // 196608 u16 each
    unsigned short* w2hi = xjB + BB * NN * DD;             // 16384 u16
    unsigned short* w1xb = w2hi + DD * DD;                 // 16384 u16
    unsigned short* wo1b = w1xb + DD * DD;                 // 16384 u16

    k_prep<<<229, 256, 0, stream>>>(Aab, embed_W, W1, b1, W2, b2, Wo1,
                                    Mtab, t2tab, ATr, w2hi, w1xb, wo1b, ctab);
    k_round0<<<512, 512, 0, stream>>>(tok, ATr, Mtab, embed_W, wo1b, bo1,
                                      Wo2, w1xb, ctab, tau_p, x, xjA);
    for (int r = 1; r < 5; ++r) {
        const unsigned short* xin = (r & 1) ? xjA : xjB;
        unsigned short*       xot = (r & 1) ? xjB : xjA;
        if (r < 4)
            k_round<0><<<512, 512, 0, stream>>>(tok, ATr, t2tab, xin, w2hi, b2,
                                                Wo1, wo1b, bo1, Wo2, embed_W, w1xb,
                                                ctab, tau_p, x, xot, out, x_all);
        else
            k_round<1><<<512, 512, 0, stream>>>(tok, ATr, t2tab, xin, w2hi, b2,
                                                Wo1, wo1b, bo1, Wo2, embed_W, w1xb,
                                                ctab, tau_p, x, xot, out, x_all);
    }
}

// Round 16
// 76.524 us; speedup vs baseline: 1.1584x; 1.1584x over previous
//
#include <hip/hip_runtime.h>
#include <hip/hip_bf16.h>
#include <math.h>

#define BB   16
#define NN   96
#define DD   128
#define NCLS 10
#define NTOK 14

typedef __attribute__((ext_vector_type(8))) short bf16x8;
typedef __attribute__((ext_vector_type(8))) unsigned short u16x8;
typedef __attribute__((ext_vector_type(4))) float f32x4;

__device__ __forceinline__ float scalar_as_float(int v) {
    if (v >= -1000000 && v <= 1000000) return (float)v;
    return __int_as_float(v);
}
__device__ __forceinline__ unsigned short f2bf(float f) {
    unsigned u = __float_as_uint(f);
    return (unsigned short)((u + 0x7FFFu + ((u >> 16) & 1u)) >> 16);
}
__device__ __forceinline__ float bf2f(unsigned short h) {
    return __uint_as_float(((unsigned)h) << 16);
}

#define MFMA(A, B, C) __builtin_amdgcn_mfma_f32_16x16x32_bf16(A, B, C, 0, 0, 0)

// XCD-chunked swizzle: HW assigns XCD = blockIdx % 8; remap so each XCD owns 64
// consecutive logical blocks = 2 complete batches -> per-XCD L2 only fills 2 batches'
// xj (48 KB) instead of all 16 (384 KB) per round. Bijective (512 = 8*64).
__device__ __forceinline__ int swz_bx() {
    const int bxr = blockIdx.x;
    return ((bxr & 7) << 6) | (bxr >> 3);
}

// ---- merged prep ----
// [0,196) Mtab(ti,tj) + t2tab | [196,212) AT | [212,220) W2 frag | [220,224) W1x bf16
// [224,228) Wo1 bf16
__global__ __launch_bounds__(256) void k_prep(
    const float* __restrict__ A, const float* __restrict__ embed_W,
    const float* __restrict__ W1, const float* __restrict__ b1,
    const float* __restrict__ W2, const float* __restrict__ b2,
    const float* __restrict__ Wo1,
    float* __restrict__ Mtab, float* __restrict__ t2tab, float* __restrict__ AT,
    unsigned short* __restrict__ w2hi, unsigned short* __restrict__ w1xb,
    unsigned short* __restrict__ wo1b)
{
    const int bx = blockIdx.x;
    const int t  = threadIdx.x;
    const float* W1x = W1 + DD * DD;

    if (bx < NTOK * NTOK) {        // Mtab(ti,tj): the only 196 distinct H rows in round 0
        const int ti = bx / NTOK, tj = bx % NTOK;
        const int d = t & 127, half = t >> 7;
        __shared__ float part[2][DD];
        __shared__ unsigned short hb[DD];
        {
            const float* erow  = embed_W + (half ? tj : ti) * DD;
            const float* wbase = half ? W1x : W1;
            float acc = 0.f;
#pragma unroll 8
            for (int k = 0; k < DD; ++k)
                acc = fmaf(erow[k], wbase[k * DD + d], acc);
            part[half][d] = acc;
        }
        __syncthreads();
        if (half == 0) {
            const float v = part[0][d] + b1[d];
            if (tj == 0) t2tab[ti * DD + d] = v;
            hb[d] = f2bf(fmaxf(v + part[1][d], 0.f));
        }
        __syncthreads();
        {
            float m = 0.f;
#pragma unroll 8
            for (int kk = 0; kk < 64; ++kk) {
                const int k = half * 64 + kk;
                m = fmaf(bf2f(hb[k]), bf2f(f2bf(W2[k * DD + d])), m);
            }
            part[half][d] = m;
        }
        __syncthreads();
        if (half == 0)
            Mtab[(ti * NTOK + tj) * DD + d] = fmaxf(part[0][d] + part[1][d] + b2[d], 0.f);
    } else if (bx < 212) {         // A transpose
        const int b = bx - 196;
        __shared__ float tile[NN][NN + 1];
        for (int idx = t; idx < NN * NN; idx += 256)
            tile[idx / NN][idx % NN] = A[b * NN * NN + idx];
        __syncthreads();
        for (int idx = t; idx < NN * NN; idx += 256) {
            const int i = idx / NN, j = idx % NN;
            AT[b * NN * NN + idx] = tile[j][i];
        }
    } else if (bx < 220) {         // W2 -> MFMA B-frag layout, bf16
        const int dt = bx - 212;
        const int kc = t >> 6, ll = t & 63;
        const int base = ((dt * 4 + kc) * 64 + ll) * 8;
        const int c = dt * 16 + (ll & 15);
#pragma unroll
        for (int e = 0; e < 8; ++e)
            w2hi[base + e] = f2bf(W2[(kc * 32 + (ll >> 4) * 8 + e) * DD + c]);
    } else if (bx < 224) {         // W1x -> bf16
        const int base = (bx - 220) * 4096 + t * 16;
#pragma unroll
        for (int e = 0; e < 16; ++e) w1xb[base + e] = f2bf(W1x[base + e]);
    } else {                       // Wo1 -> bf16 (DISC rounds only)
        const int base = (bx - 224) * 4096 + t * 16;
#pragma unroll
        for (int e = 0; e < 16; ++e) wo1b[base + e] = f2bf(Wo1[base + e]);
    }
}

// -------- round 0 fast path: agg = A-weighted gather-sum over Mtab --------
__global__ __launch_bounds__(512, 4) void k_round0(
    const int* __restrict__ tok, const float* __restrict__ AT,
    const float* __restrict__ Mtab, const float* __restrict__ embed_W,
    const unsigned short* __restrict__ wo1b, const float* __restrict__ bo1,
    const float* __restrict__ Wo2, const unsigned short* __restrict__ w1xb,
    const int* __restrict__ tau_p,
    float* __restrict__ x, unsigned short* __restrict__ xj_out)
{
    const int bx = swz_bx();
    const int b  = bx >> 5;
    const int is = bx & 31;
    const int t  = threadIdx.x;
    const int w  = t >> 6;
    const int l  = t & 63;
    const int row0 = b * NN + is;

    __shared__ __align__(16) float mt[3][NTOK * DD];
    __shared__ float at3[3][NN];
    __shared__ int   tkj[NN];
    __shared__ float agg_s[3][DD];
    __shared__ float xn_s[3][DD];
    __shared__ float part_s[4][3][DD];

    const int ti0 = tok[row0], ti1 = tok[row0 + 32], ti2 = tok[row0 + 64];
    if (t < NN) {
        tkj[t]    = tok[b * NN + t];
        at3[0][t] = AT[row0 * NN + t];
        at3[1][t] = AT[(row0 + 32) * NN + t];
        at3[2][t] = AT[(row0 + 64) * NN + t];
    }
    for (int idx = t; idx < 3 * NTOK * DD; idx += 512) {
        const int u = idx / (NTOK * DD), rd = idx - u * (NTOK * DD);
        const int tiu = (u == 0) ? ti0 : ((u == 1) ? ti1 : ti2);
        mt[u][rd] = Mtab[tiu * NTOK * DD + rd];
    }
    __syncthreads();

    if (t < 192) {
        const int u = t >> 6, d2 = t & 63;
        const float2* mtu = (const float2*)mt[u];
        float2 acc = {0.f, 0.f};
#pragma unroll 4
        for (int j = 0; j < NN; ++j) {
            const float a = at3[u][j];
            const float2 m = mtu[tkj[j] * 64 + d2];
            acc.x = fmaf(a, m.x, acc.x);
            acc.y = fmaf(a, m.y, acc.y);
        }
        *(float2*)&agg_s[u][d2 * 2] = acc;
    }
    __syncthreads();

    float xr0 = 0.f, xr1 = 0.f;
    if (w < 3) {
        const int tk = (w == 0) ? ti0 : ((w == 1) ? ti1 : ti2);
        xr0 = embed_W[tk * DD + l]      + agg_s[w][l];
        xr1 = embed_W[tk * DD + l + 64] + agg_s[w][l + 64];
        xn_s[w][l]      = xr0;
        xn_s[w][l + 64] = xr1;
    }
    __syncthreads();

    {   // hid partials, Wo1 bf16
        const int q = t >> 7, h = t & 127;
        float p0 = 0.f, p1 = 0.f, p2 = 0.f;
#pragma unroll
        for (int kk = 0; kk < 32; ++kk) {
            const int k = q * 32 + kk;
            const float wv = bf2f(wo1b[k * DD + h]);
            p0 = fmaf(xn_s[0][k], wv, p0);
            p1 = fmaf(xn_s[1][k], wv, p1);
            p2 = fmaf(xn_s[2][k], wv, p2);
        }
        part_s[q][0][h] = p0; part_s[q][1][h] = p1; part_s[q][2][h] = p2;
    }
    __syncthreads();

    if (w < 3) {
        const int row_u = row0 + 32 * w;
        const float hid0 = fmaxf(part_s[0][w][l] + part_s[1][w][l]
                               + part_s[2][w][l] + part_s[3][w][l] + bo1[l], 0.f);
        const float hid1 = fmaxf(part_s[0][w][l + 64] + part_s[1][w][l + 64]
                               + part_s[2][w][l + 64] + part_s[3][w][l + 64] + bo1[l + 64], 0.f);
        float lgp[NCLS];
#pragma unroll
        for (int c = 0; c < NCLS; ++c)
            lgp[c] = hid0 * Wo2[l * NCLS + c] + hid1 * Wo2[(l + 64) * NCLS + c];
#pragma unroll
        for (int s = 1; s < 64; s <<= 1) {
#pragma unroll
            for (int c = 0; c < NCLS; ++c) lgp[c] += __shfl_xor(lgp[c], s);
        }
        float mx = -1e30f;
#pragma unroll
        for (int c = 0; c < NCLS; ++c) mx = fmaxf(mx, lgp[c]);
        const float inv_tau = 1.f / scalar_as_float(tau_p[0]);
        float p[NCLS], den = 0.f;
#pragma unroll
        for (int c = 0; c < NCLS; ++c) { p[c] = expf((lgp[c] - mx) * inv_tau); den += p[c]; }
        const float invden = 1.f / den;
#pragma unroll
        for (int c = 0; c < NCLS; ++c) {
            const float pc = p[c] * invden;
            xr0 = fmaf(pc, embed_W[(4 + c) * DD + l], xr0);
            xr1 = fmaf(pc, embed_W[(4 + c) * DD + l + 64], xr1);
        }
        x[row_u * DD + l]      = xr0;
        x[row_u * DD + l + 64] = xr1;
        xn_s[w][l]      = xr0;
        xn_s[w][l + 64] = xr1;
    }
    __syncthreads();

    {   // next-round xj partials (W1x bf16)
        const int q = t >> 7, h = t & 127;
        float p0 = 0.f, p1 = 0.f, p2 = 0.f;
#pragma unroll
        for (int kk = 0; kk < 32; ++kk) {
            const int k = q * 32 + kk;
            const float wv = bf2f(w1xb[k * DD + h]);
            p0 = fmaf(xn_s[0][k], wv, p0);
            p1 = fmaf(xn_s[1][k], wv, p1);
            p2 = fmaf(xn_s[2][k], wv, p2);
        }
        part_s[q][0][h] = p0; part_s[q][1][h] = p1; part_s[q][2][h] = p2;
    }
    __syncthreads();

    if (w < 3) {
        const int row_u = row0 + 32 * w;
        xj_out[row_u * DD + l] =
            f2bf(part_s[0][w][l] + part_s[1][w][l] + part_s[2][w][l] + part_s[3][w][l]);
        xj_out[row_u * DD + l + 64] =
            f2bf(part_s[0][w][l + 64] + part_s[1][w][l + 64]
               + part_s[2][w][l + 64] + part_s[3][w][l + 64]);
    }
}

// -------- rounds 1..4: 3-unit pipelined MFMA GEMM + one-wave-per-row epilogue --------
// (R13 structure verbatim: separate P2 hid / P5 xj matvec phases — the R14/R15 fused
// dual-matvec variants both regressed ~9us in clean A/B.)
template<int FIN>
__global__ __launch_bounds__(512, 4) void k_round(
    const int* __restrict__ tok, const float* __restrict__ AT,
    const float* __restrict__ t2tab,
    const unsigned short* __restrict__ xj_in,
    const unsigned short* __restrict__ w2hi, const float* __restrict__ b2,
    const float* __restrict__ Wo1, const unsigned short* __restrict__ wo1b,
    const float* __restrict__ bo1, const float* __restrict__ Wo2,
    const float* __restrict__ embed_W, const unsigned short* __restrict__ w1xb,
    const int* __restrict__ tau_p,
    float* __restrict__ x, unsigned short* __restrict__ xj_out,
    float* __restrict__ out, float* __restrict__ x_all)
{
    const int bx = swz_bx();
    const int b  = bx >> 5;
    const int is = bx & 31;
    const int t  = threadIdx.x;
    const int w  = t >> 6;
    const int l  = t & 63;
    const int jg  = w >> 2;
    const int dg  = w & 3;
    const int jg3 = jg * 3;
    const int d0 = (t & 15) * 8;
    const int row0 = b * NN + is;

    __shared__ __align__(16) unsigned short hs[2][NN * DD];
    __shared__ float ac_s[2][NN];
    __shared__ float agg_part[3][2][DD];
    __shared__ float xn_s[3][DD];
    __shared__ float part_s[4][3][DD];

    const int tk0 = tok[row0], tk1 = tok[row0 + 32], tk2 = tok[row0 + 64];

    const bf16x8* WH = (const bf16x8*)w2hi;
    const int f0 = (dg * 4) * 64 + l;
    const int f1 = ((dg + 4) * 4) * 64 + l;
    bf16x8 bh00 = WH[f0],        bh10 = WH[f1];
    bf16x8 bh01 = WH[f0 + 64],   bh11 = WH[f1 + 64];
    bf16x8 bh02 = WH[f0 + 128],  bh12 = WH[f1 + 128];
    bf16x8 bh03 = WH[f0 + 192],  bh13 = WH[f1 + 192];
    asm volatile("" : "+v"(bh00), "+v"(bh01), "+v"(bh02), "+v"(bh03),
                      "+v"(bh10), "+v"(bh11), "+v"(bh12), "+v"(bh13));
    const float b2v0 = b2[dg * 16 + (l & 15)];
    const float b2v1 = b2[64 + dg * 16 + (l & 15)];
    const u16x8* xj8 = (const u16x8*)(xj_in + b * NN * DD);

    auto STAGE = [&](int u, int p) {
        const int row_u = row0 + 32 * u;
        const int tk = (u == 0) ? tk0 : ((u == 1) ? tk1 : tk2);
        const float4 ea = *(const float4*)(t2tab + tk * DD + d0);
        const float4 eb = *(const float4*)(t2tab + tk * DD + d0 + 4);
        float v8[8];
        v8[0] = ea.x; v8[1] = ea.y; v8[2] = ea.z; v8[3] = ea.w;
        v8[4] = eb.x; v8[5] = eb.y; v8[6] = eb.z; v8[7] = eb.w;
        if (t < NN) ac_s[p][t] = AT[row_u * NN + t];
#pragma unroll
        for (int it = 0; it < 3; ++it) {
            const int idx8 = t + it * 512;
            const int j = idx8 >> 4;
            const u16x8 xv = xj8[idx8];
            u16x8 hh;
#pragma unroll
            for (int e = 0; e < 8; ++e)
                hh[e] = f2bf(fmaxf(bf2f(xv[e]) + v8[e], 0.f));
            *(u16x8*)&hs[p][(j * DD + d0) ^ ((j & 7) << 3)] = hh;
        }
    };

    auto GEMM = [&](int u, int p) {
        float aggp0 = 0.f, aggp1 = 0.f;
        const unsigned short* hb = hs[p];
#pragma unroll
        for (int jj = 0; jj < 3; ++jj) {
            const int jt  = jg3 + jj;
            const int r16 = jt * 16 + (l & 15);
            const int ko  = (l >> 4) * 8;
            const int sw  = (r16 & 7) << 3;
            const bf16x8 a0 = *(const bf16x8*)&hb[(r16 * DD + ko     ) ^ sw];
            const bf16x8 a1 = *(const bf16x8*)&hb[(r16 * DD + ko + 32) ^ sw];
            const bf16x8 a2 = *(const bf16x8*)&hb[(r16 * DD + ko + 64) ^ sw];
            const bf16x8 a3 = *(const bf16x8*)&hb[(r16 * DD + ko + 96) ^ sw];
            f32x4 c0 = {0.f, 0.f, 0.f, 0.f}, c1 = {0.f, 0.f, 0.f, 0.f};
            c0 = MFMA(a0, bh00, c0);  c1 = MFMA(a0, bh10, c1);
            c0 = MFMA(a1, bh01, c0);  c1 = MFMA(a1, bh11, c1);
            c0 = MFMA(a2, bh02, c0);  c1 = MFMA(a2, bh12, c1);
            c0 = MFMA(a3, bh03, c0);  c1 = MFMA(a3, bh13, c1);
#pragma unroll
            for (int r = 0; r < 4; ++r) {
                const float a = ac_s[p][jt * 16 + (l >> 4) * 4 + r];
                aggp0 = fmaf(a, fmaxf(c0[r] + b2v0, 0.f), aggp0);
                aggp1 = fmaf(a, fmaxf(c1[r] + b2v1, 0.f), aggp1);
            }
        }
        aggp0 += __shfl_xor(aggp0, 16); aggp0 += __shfl_xor(aggp0, 32);
        aggp1 += __shfl_xor(aggp1, 16); aggp1 += __shfl_xor(aggp1, 32);
        if (l < 16) {
            agg_part[u][jg][dg * 16 + l]      = aggp0;
            agg_part[u][jg][64 + dg * 16 + l] = aggp1;
        }
    };

    STAGE(0, 0);
    __syncthreads();
    STAGE(1, 1);
    GEMM(0, 0);
    __syncthreads();
    STAGE(2, 0);
    GEMM(1, 1);
    __syncthreads();
    GEMM(2, 0);
    __syncthreads();

    // P1: x update
    float xr0 = 0.f, xr1 = 0.f;
    if (w < 3) {
        const int row_u = row0 + 32 * w;
        xr0 = x[row_u * DD + l]      + agg_part[w][0][l]      + agg_part[w][1][l];
        xr1 = x[row_u * DD + l + 64] + agg_part[w][0][l + 64] + agg_part[w][1][l + 64];
        xn_s[w][l]      = xr0;
        xn_s[w][l + 64] = xr1;
    }
    __syncthreads();

    // P2: hid partials (Wo1 fp32 for FIN, bf16 for DISC)
    {
        const int q = t >> 7, h = t & 127;
        float p0 = 0.f, p1 = 0.f, p2 = 0.f;
#pragma unroll
        for (int kk = 0; kk < 32; ++kk) {
            const int k = q * 32 + kk;
            const float wv = FIN ? Wo1[k * DD + h] : bf2f(wo1b[k * DD + h]);
            p0 = fmaf(xn_s[0][k], wv, p0);
            p1 = fmaf(xn_s[1][k], wv, p1);
            p2 = fmaf(xn_s[2][k], wv, p2);
        }
        part_s[q][0][h] = p0; part_s[q][1][h] = p1; part_s[q][2][h] = p2;
    }
    __syncthreads();

    // P3: hid + logits + [FIN store | softmax + x update]
    if (w < 3) {
        const int row_u = row0 + 32 * w;
        const float hid0 = fmaxf(part_s[0][w][l] + part_s[1][w][l]
                               + part_s[2][w][l] + part_s[3][w][l] + bo1[l], 0.f);
        const float hid1 = fmaxf(part_s[0][w][l + 64] + part_s[1][w][l + 64]
                               + part_s[2][w][l + 64] + part_s[3][w][l + 64] + bo1[l + 64], 0.f);
        float lgp[NCLS];
#pragma unroll
        for (int c = 0; c < NCLS; ++c)
            lgp[c] = hid0 * Wo2[l * NCLS + c] + hid1 * Wo2[(l + 64) * NCLS + c];
#pragma unroll
        for (int s = 1; s < 64; s <<= 1) {
#pragma unroll
            for (int c = 0; c < NCLS; ++c) lgp[c] += __shfl_xor(lgp[c], s);
        }
        if (FIN) {
#pragma unroll
            for (int c = 0; c < NCLS; ++c) {
                if (l == c) {
                    x_all[row_u * NCLS + c] = lgp[c];
                    if (is == 0 && w == 0) out[b * NCLS + c] = lgp[c];
                }
            }
        } else {
            float mx = -1e30f;
#pragma unroll
            for (int c = 0; c < NCLS; ++c) mx = fmaxf(mx, lgp[c]);
            const float inv_tau = 1.f / scalar_as_float(tau_p[0]);
            float p[NCLS], den = 0.f;
#pragma unroll
            for (int c = 0; c < NCLS; ++c) { p[c] = expf((lgp[c] - mx) * inv_tau); den += p[c]; }
            const float invden = 1.f / den;
#pragma unroll
            for (int c = 0; c < NCLS; ++c) {
                const float pc = p[c] * invden;
                xr0 = fmaf(pc, embed_W[(4 + c) * DD + l], xr0);
                xr1 = fmaf(pc, embed_W[(4 + c) * DD + l + 64], xr1);
            }
            x[row_u * DD + l]      = xr0;
            x[row_u * DD + l + 64] = xr1;
            xn_s[w][l]      = xr0;
            xn_s[w][l + 64] = xr1;
        }
    }
    if (FIN) return;
    __syncthreads();

    // P5: next-round xj partials (W1x bf16)
    {
        const int q = t >> 7, h = t & 127;
        float p0 = 0.f, p1 = 0.f, p2 = 0.f;
#pragma unroll
        for (int kk = 0; kk < 32; ++kk) {
            const int k = q * 32 + kk;
            const float wv = bf2f(w1xb[k * DD + h]);
            p0 = fmaf(xn_s[0][k], wv, p0);
            p1 = fmaf(xn_s[1][k], wv, p1);
            p2 = fmaf(xn_s[2][k], wv, p2);
        }
        part_s[q][0][h] = p0; part_s[q][1][h] = p1; part_s[q][2][h] = p2;
    }
    __syncthreads();

    // P6: gather + store xj bf16
    if (w < 3) {
        const int row_u = row0 + 32 * w;
        xj_out[row_u * DD + l] =
            f2bf(part_s[0][w][l] + part_s[1][w][l] + part_s[2][w][l] + part_s[3][w][l]);
        xj_out[row_u * DD + l + 64] =
            f2bf(part_s[0][w][l + 64] + part_s[1][w][l + 64]
               + part_s[2][w][l + 64] + part_s[3][w][l + 64]);
    }
}

extern "C" void kernel_launch(void* const* d_in, const int* in_sizes, int n_in,
                              void* d_out, int out_size, void* d_ws, size_t ws_size,
                              hipStream_t stream)
{
    (void)in_sizes; (void)n_in; (void)out_size; (void)ws_size;
    const int*   tok     = (const int*)d_in[0];
    const float* Aab     = (const float*)d_in[1];
    const float* embed_W = (const float*)d_in[2];
    const float* W1      = (const float*)d_in[3];
    const float* b1      = (const float*)d_in[4];
    const float* W2      = (const float*)d_in[5];
    const float* b2      = (const float*)d_in[6];
    const float* Wo1     = (const float*)d_in[7];
    const float* bo1     = (const float*)d_in[8];
    const float* Wo2     = (const float*)d_in[9];
    const int*   tau_p   = (const int*)d_in[11];

    float* out   = (float*)d_out;
    float* x_all = out + BB * NCLS;

    float* ws     = (float*)d_ws;
    float* x      = ws;                                    // 196608 f
    float* ATr    = ws + BB * NN * DD;                     // 147456 f
    float* Mtab   = ATr + BB * NN * NN;                    // 25088 f
    float* t2tab  = Mtab + NTOK * NTOK * DD;               // 1792 f
    unsigned short* xjA  = (unsigned short*)(t2tab + NTOK * DD);
    unsigned short* xjB  = xjA + BB * NN * DD;             // 196608 u16 each
    unsigned short* w2hi = xjB + BB * NN * DD;             // 16384 u16
    unsigned short* w1xb = w2hi + DD * DD;                 // 16384 u16
    unsigned short* wo1b = w1xb + DD * DD;                 // 16384 u16

    k_prep<<<228, 256, 0, stream>>>(Aab, embed_W, W1, b1, W2, b2, Wo1,
                                    Mtab, t2tab, ATr, w2hi, w1xb, wo1b);
    k_round0<<<512, 512, 0, stream>>>(tok, ATr, Mtab, embed_W, wo1b, bo1,
                                      Wo2, w1xb, tau_p, x, xjA);
    for (int r = 1; r < 5; ++r) {
        const unsigned short* xin = (r & 1) ? xjA : xjB;
        unsigned short*       xot = (r & 1) ? xjB : xjA;
        if (r < 4)
            k_round<0><<<512, 512, 0, stream>>>(tok, ATr, t2tab, xin, w2hi, b2,
                                                Wo1, wo1b, bo1, Wo2, embed_W, w1xb,
                                                tau_p, x, xot, out, x_all);
        else
            k_round<1><<<512, 512, 0, stream>>>(tok, ATr, t2tab, xin, w2hi, b2,
                                                Wo1, wo1b, bo1, Wo2, embed_W, w1xb,
                                                tau_p, x, xot, out, x_all);
    }
}

// Round 17
// 75.296 us; speedup vs baseline: 1.1773x; 1.0163x over previous
//
#include <hip/hip_runtime.h>
#include <hip/hip_bf16.h>
#include <math.h>

#define BB   16
#define NN   96
#define DD   128
#define NCLS 10
#define NTOK 14

typedef __attribute__((ext_vector_type(8))) short bf16x8;
typedef __attribute__((ext_vector_type(8))) unsigned short u16x8;
typedef __attribute__((ext_vector_type(4))) float f32x4;

__device__ __forceinline__ float scalar_as_float(int v) {
    if (v >= -1000000 && v <= 1000000) return (float)v;
    return __int_as_float(v);
}
// explicit RNE bit-twiddle (cold paths / prep only)
__device__ __forceinline__ unsigned short f2bf(float f) {
    unsigned u = __float_as_uint(f);
    return (unsigned short)((u + 0x7FFFu + ((u >> 16) & 1u)) >> 16);
}
// hot-path RNE convert via native cast: compiler emits v_cvt_pk_bf16_f32 pairs
// (learn_hip m240: scalar cast > hand-rolled bit math; our f2bf is ~4 VALU/elem)
__device__ __forceinline__ unsigned short f2bf_fast(float f) {
    __hip_bfloat16 b = __float2bfloat16(f);
    return *reinterpret_cast<unsigned short*>(&b);
}
__device__ __forceinline__ float bf2f(unsigned short h) {
    return __uint_as_float(((unsigned)h) << 16);
}

#define MFMA(A, B, C) __builtin_amdgcn_mfma_f32_16x16x32_bf16(A, B, C, 0, 0, 0)

// XCD-chunked swizzle: HW assigns XCD = blockIdx % 8; remap so each XCD owns 64
// consecutive logical blocks = 2 complete batches -> per-XCD L2 only fills 2 batches'
// xj (48 KB) instead of all 16 (384 KB) per round. Bijective (512 = 8*64).
__device__ __forceinline__ int swz_bx() {
    const int bxr = blockIdx.x;
    return ((bxr & 7) << 6) | (bxr >> 3);
}

// ---- merged prep ----
// [0,196) Mtab(ti,tj) + t2tab | [196,212) AT | [212,220) W2 frag | [220,224) W1x bf16
// [224,228) Wo1 bf16
__global__ __launch_bounds__(256) void k_prep(
    const float* __restrict__ A, const float* __restrict__ embed_W,
    const float* __restrict__ W1, const float* __restrict__ b1,
    const float* __restrict__ W2, const float* __restrict__ b2,
    const float* __restrict__ Wo1,
    float* __restrict__ Mtab, float* __restrict__ t2tab, float* __restrict__ AT,
    unsigned short* __restrict__ w2hi, unsigned short* __restrict__ w1xb,
    unsigned short* __restrict__ wo1b)
{
    const int bx = blockIdx.x;
    const int t  = threadIdx.x;
    const float* W1x = W1 + DD * DD;

    if (bx < NTOK * NTOK) {        // Mtab(ti,tj): the only 196 distinct H rows in round 0
        const int ti = bx / NTOK, tj = bx % NTOK;
        const int d = t & 127, half = t >> 7;
        __shared__ float part[2][DD];
        __shared__ unsigned short hb[DD];
        {
            const float* erow  = embed_W + (half ? tj : ti) * DD;
            const float* wbase = half ? W1x : W1;
            float acc = 0.f;
#pragma unroll 8
            for (int k = 0; k < DD; ++k)
                acc = fmaf(erow[k], wbase[k * DD + d], acc);
            part[half][d] = acc;
        }
        __syncthreads();
        if (half == 0) {
            const float v = part[0][d] + b1[d];
            if (tj == 0) t2tab[ti * DD + d] = v;
            hb[d] = f2bf(fmaxf(v + part[1][d], 0.f));
        }
        __syncthreads();
        {
            float m = 0.f;
#pragma unroll 8
            for (int kk = 0; kk < 64; ++kk) {
                const int k = half * 64 + kk;
                m = fmaf(bf2f(hb[k]), bf2f(f2bf(W2[k * DD + d])), m);
            }
            part[half][d] = m;
        }
        __syncthreads();
        if (half == 0)
            Mtab[(ti * NTOK + tj) * DD + d] = fmaxf(part[0][d] + part[1][d] + b2[d], 0.f);
    } else if (bx < 212) {         // A transpose
        const int b = bx - 196;
        __shared__ float tile[NN][NN + 1];
        for (int idx = t; idx < NN * NN; idx += 256)
            tile[idx / NN][idx % NN] = A[b * NN * NN + idx];
        __syncthreads();
        for (int idx = t; idx < NN * NN; idx += 256) {
            const int i = idx / NN, j = idx % NN;
            AT[b * NN * NN + idx] = tile[j][i];
        }
    } else if (bx < 220) {         // W2 -> MFMA B-frag layout, bf16
        const int dt = bx - 212;
        const int kc = t >> 6, ll = t & 63;
        const int base = ((dt * 4 + kc) * 64 + ll) * 8;
        const int c = dt * 16 + (ll & 15);
#pragma unroll
        for (int e = 0; e < 8; ++e)
            w2hi[base + e] = f2bf(W2[(kc * 32 + (ll >> 4) * 8 + e) * DD + c]);
    } else if (bx < 224) {         // W1x -> bf16
        const int base = (bx - 220) * 4096 + t * 16;
#pragma unroll
        for (int e = 0; e < 16; ++e) w1xb[base + e] = f2bf(W1x[base + e]);
    } else {                       // Wo1 -> bf16 (DISC rounds only)
        const int base = (bx - 224) * 4096 + t * 16;
#pragma unroll
        for (int e = 0; e < 16; ++e) wo1b[base + e] = f2bf(Wo1[base + e]);
    }
}

// -------- round 0 fast path: agg = A-weighted gather-sum over Mtab --------
__global__ __launch_bounds__(512, 4) void k_round0(
    const int* __restrict__ tok, const float* __restrict__ AT,
    const float* __restrict__ Mtab, const float* __restrict__ embed_W,
    const unsigned short* __restrict__ wo1b, const float* __restrict__ bo1,
    const float* __restrict__ Wo2, const unsigned short* __restrict__ w1xb,
    const int* __restrict__ tau_p,
    float* __restrict__ x, unsigned short* __restrict__ xj_out)
{
    const int bx = swz_bx();
    const int b  = bx >> 5;
    const int is = bx & 31;
    const int t  = threadIdx.x;
    const int w  = t >> 6;
    const int l  = t & 63;
    const int row0 = b * NN + is;

    __shared__ __align__(16) float mt[3][NTOK * DD];
    __shared__ float at3[3][NN];
    __shared__ int   tkj[NN];
    __shared__ float agg_s[3][DD];
    __shared__ float xn_s[3][DD];
    __shared__ float part_s[4][3][DD];

    const int ti0 = tok[row0], ti1 = tok[row0 + 32], ti2 = tok[row0 + 64];
    if (t < NN) {
        tkj[t]    = tok[b * NN + t];
        at3[0][t] = AT[row0 * NN + t];
        at3[1][t] = AT[(row0 + 32) * NN + t];
        at3[2][t] = AT[(row0 + 64) * NN + t];
    }
    for (int idx = t; idx < 3 * NTOK * DD; idx += 512) {
        const int u = idx / (NTOK * DD), rd = idx - u * (NTOK * DD);
        const int tiu = (u == 0) ? ti0 : ((u == 1) ? ti1 : ti2);
        mt[u][rd] = Mtab[tiu * NTOK * DD + rd];
    }
    __syncthreads();

    if (t < 192) {
        const int u = t >> 6, d2 = t & 63;
        const float2* mtu = (const float2*)mt[u];
        float2 acc = {0.f, 0.f};
#pragma unroll 4
        for (int j = 0; j < NN; ++j) {
            const float a = at3[u][j];
            const float2 m = mtu[tkj[j] * 64 + d2];
            acc.x = fmaf(a, m.x, acc.x);
            acc.y = fmaf(a, m.y, acc.y);
        }
        *(float2*)&agg_s[u][d2 * 2] = acc;
    }
    __syncthreads();

    float xr0 = 0.f, xr1 = 0.f;
    if (w < 3) {
        const int tk = (w == 0) ? ti0 : ((w == 1) ? ti1 : ti2);
        xr0 = embed_W[tk * DD + l]      + agg_s[w][l];
        xr1 = embed_W[tk * DD + l + 64] + agg_s[w][l + 64];
        xn_s[w][l]      = xr0;
        xn_s[w][l + 64] = xr1;
    }
    __syncthreads();

    {   // hid partials, Wo1 bf16
        const int q = t >> 7, h = t & 127;
        float p0 = 0.f, p1 = 0.f, p2 = 0.f;
#pragma unroll
        for (int kk = 0; kk < 32; ++kk) {
            const int k = q * 32 + kk;
            const float wv = bf2f(wo1b[k * DD + h]);
            p0 = fmaf(xn_s[0][k], wv, p0);
            p1 = fmaf(xn_s[1][k], wv, p1);
            p2 = fmaf(xn_s[2][k], wv, p2);
        }
        part_s[q][0][h] = p0; part_s[q][1][h] = p1; part_s[q][2][h] = p2;
    }
    __syncthreads();

    if (w < 3) {
        const int row_u = row0 + 32 * w;
        const float hid0 = fmaxf(part_s[0][w][l] + part_s[1][w][l]
                               + part_s[2][w][l] + part_s[3][w][l] + bo1[l], 0.f);
        const float hid1 = fmaxf(part_s[0][w][l + 64] + part_s[1][w][l + 64]
                               + part_s[2][w][l + 64] + part_s[3][w][l + 64] + bo1[l + 64], 0.f);
        float lgp[NCLS];
#pragma unroll
        for (int c = 0; c < NCLS; ++c)
            lgp[c] = hid0 * Wo2[l * NCLS + c] + hid1 * Wo2[(l + 64) * NCLS + c];
#pragma unroll
        for (int s = 1; s < 64; s <<= 1) {
#pragma unroll
            for (int c = 0; c < NCLS; ++c) lgp[c] += __shfl_xor(lgp[c], s);
        }
        float mx = -1e30f;
#pragma unroll
        for (int c = 0; c < NCLS; ++c) mx = fmaxf(mx, lgp[c]);
        const float inv_tau = 1.f / scalar_as_float(tau_p[0]);
        float p[NCLS], den = 0.f;
#pragma unroll
        for (int c = 0; c < NCLS; ++c) { p[c] = expf((lgp[c] - mx) * inv_tau); den += p[c]; }
        const float invden = 1.f / den;
#pragma unroll
        for (int c = 0; c < NCLS; ++c) {
            const float pc = p[c] * invden;
            xr0 = fmaf(pc, embed_W[(4 + c) * DD + l], xr0);
            xr1 = fmaf(pc, embed_W[(4 + c) * DD + l + 64], xr1);
        }
        x[row_u * DD + l]      = xr0;
        x[row_u * DD + l + 64] = xr1;
        xn_s[w][l]      = xr0;
        xn_s[w][l + 64] = xr1;
    }
    __syncthreads();

    {   // next-round xj partials (W1x bf16)
        const int q = t >> 7, h = t & 127;
        float p0 = 0.f, p1 = 0.f, p2 = 0.f;
#pragma unroll
        for (int kk = 0; kk < 32; ++kk) {
            const int k = q * 32 + kk;
            const float wv = bf2f(w1xb[k * DD + h]);
            p0 = fmaf(xn_s[0][k], wv, p0);
            p1 = fmaf(xn_s[1][k], wv, p1);
            p2 = fmaf(xn_s[2][k], wv, p2);
        }
        part_s[q][0][h] = p0; part_s[q][1][h] = p1; part_s[q][2][h] = p2;
    }
    __syncthreads();

    if (w < 3) {
        const int row_u = row0 + 32 * w;
        xj_out[row_u * DD + l] =
            f2bf_fast(part_s[0][w][l] + part_s[1][w][l] + part_s[2][w][l] + part_s[3][w][l]);
        xj_out[row_u * DD + l + 64] =
            f2bf_fast(part_s[0][w][l + 64] + part_s[1][w][l + 64]
                    + part_s[2][w][l + 64] + part_s[3][w][l + 64]);
    }
}

// -------- rounds 1..4: 3-unit pipelined MFMA GEMM + one-wave-per-row epilogue --------
template<int FIN>
__global__ __launch_bounds__(512, 4) void k_round(
    const int* __restrict__ tok, const float* __restrict__ AT,
    const float* __restrict__ t2tab,
    const unsigned short* __restrict__ xj_in,
    const unsigned short* __restrict__ w2hi, const float* __restrict__ b2,
    const float* __restrict__ Wo1, const unsigned short* __restrict__ wo1b,
    const float* __restrict__ bo1, const float* __restrict__ Wo2,
    const float* __restrict__ embed_W, const unsigned short* __restrict__ w1xb,
    const int* __restrict__ tau_p,
    float* __restrict__ x, unsigned short* __restrict__ xj_out,
    float* __restrict__ out, float* __restrict__ x_all)
{
    const int bx = swz_bx();
    const int b  = bx >> 5;
    const int is = bx & 31;
    const int t  = threadIdx.x;
    const int w  = t >> 6;
    const int l  = t & 63;
    const int jg  = w >> 2;
    const int dg  = w & 3;
    const int jg3 = jg * 3;
    const int d0 = (t & 15) * 8;
    const int row0 = b * NN + is;

    __shared__ __align__(16) unsigned short hs[2][NN * DD];
    __shared__ float ac_s[2][NN];
    __shared__ float agg_part[3][2][DD];
    __shared__ float xn_s[3][DD];
    __shared__ float part_s[4][3][DD];

    const int tk0 = tok[row0], tk1 = tok[row0 + 32], tk2 = tok[row0 + 64];

    const bf16x8* WH = (const bf16x8*)w2hi;
    const int f0 = (dg * 4) * 64 + l;
    const int f1 = ((dg + 4) * 4) * 64 + l;
    bf16x8 bh00 = WH[f0],        bh10 = WH[f1];
    bf16x8 bh01 = WH[f0 + 64],   bh11 = WH[f1 + 64];
    bf16x8 bh02 = WH[f0 + 128],  bh12 = WH[f1 + 128];
    bf16x8 bh03 = WH[f0 + 192],  bh13 = WH[f1 + 192];
    asm volatile("" : "+v"(bh00), "+v"(bh01), "+v"(bh02), "+v"(bh03),
                      "+v"(bh10), "+v"(bh11), "+v"(bh12), "+v"(bh13));
    const float b2v0 = b2[dg * 16 + (l & 15)];
    const float b2v1 = b2[64 + dg * 16 + (l & 15)];
    const u16x8* xj8 = (const u16x8*)(xj_in + b * NN * DD);

    auto STAGE = [&](int u, int p) {
        const int row_u = row0 + 32 * u;
        const int tk = (u == 0) ? tk0 : ((u == 1) ? tk1 : tk2);
        const float4 ea = *(const float4*)(t2tab + tk * DD + d0);
        const float4 eb = *(const float4*)(t2tab + tk * DD + d0 + 4);
        float v8[8];
        v8[0] = ea.x; v8[1] = ea.y; v8[2] = ea.z; v8[3] = ea.w;
        v8[4] = eb.x; v8[5] = eb.y; v8[6] = eb.z; v8[7] = eb.w;
        if (t < NN) ac_s[p][t] = AT[row_u * NN + t];
#pragma unroll
        for (int it = 0; it < 3; ++it) {
            const int idx8 = t + it * 512;
            const int j = idx8 >> 4;
            const u16x8 xv = xj8[idx8];
            u16x8 hh;
#pragma unroll
            for (int e = 0; e < 8; ++e)
                hh[e] = f2bf_fast(fmaxf(bf2f(xv[e]) + v8[e], 0.f));
            *(u16x8*)&hs[p][(j * DD + d0) ^ ((j & 7) << 3)] = hh;
        }
    };

    auto GEMM = [&](int u, int p) {
        float aggp0 = 0.f, aggp1 = 0.f;
        const unsigned short* hb = hs[p];
#pragma unroll
        for (int jj = 0; jj < 3; ++jj) {
            const int jt  = jg3 + jj;
            const int r16 = jt * 16 + (l & 15);
            const int ko  = (l >> 4) * 8;
            const int sw  = (r16 & 7) << 3;
            const bf16x8 a0 = *(const bf16x8*)&hb[(r16 * DD + ko     ) ^ sw];
            const bf16x8 a1 = *(const bf16x8*)&hb[(r16 * DD + ko + 32) ^ sw];
            const bf16x8 a2 = *(const bf16x8*)&hb[(r16 * DD + ko + 64) ^ sw];
            const bf16x8 a3 = *(const bf16x8*)&hb[(r16 * DD + ko + 96) ^ sw];
            f32x4 c0 = {0.f, 0.f, 0.f, 0.f}, c1 = {0.f, 0.f, 0.f, 0.f};
            c0 = MFMA(a0, bh00, c0);  c1 = MFMA(a0, bh10, c1);
            c0 = MFMA(a1, bh01, c0);  c1 = MFMA(a1, bh11, c1);
            c0 = MFMA(a2, bh02, c0);  c1 = MFMA(a2, bh12, c1);
            c0 = MFMA(a3, bh03, c0);  c1 = MFMA(a3, bh13, c1);
#pragma unroll
            for (int r = 0; r < 4; ++r) {
                const float a = ac_s[p][jt * 16 + (l >> 4) * 4 + r];
                aggp0 = fmaf(a, fmaxf(c0[r] + b2v0, 0.f), aggp0);
                aggp1 = fmaf(a, fmaxf(c1[r] + b2v1, 0.f), aggp1);
            }
        }
        aggp0 += __shfl_xor(aggp0, 16); aggp0 += __shfl_xor(aggp0, 32);
        aggp1 += __shfl_xor(aggp1, 16); aggp1 += __shfl_xor(aggp1, 32);
        if (l < 16) {
            agg_part[u][jg][dg * 16 + l]      = aggp0;
            agg_part[u][jg][64 + dg * 16 + l] = aggp1;
        }
    };

    STAGE(0, 0);
    __syncthreads();
    STAGE(1, 1);
    GEMM(0, 0);
    __syncthreads();
    STAGE(2, 0);
    GEMM(1, 1);
    __syncthreads();
    GEMM(2, 0);
    __syncthreads();

    // P1: x update
    float xr0 = 0.f, xr1 = 0.f;
    if (w < 3) {
        const int row_u = row0 + 32 * w;
        xr0 = x[row_u * DD + l]      + agg_part[w][0][l]      + agg_part[w][1][l];
        xr1 = x[row_u * DD + l + 64] + agg_part[w][0][l + 64] + agg_part[w][1][l + 64];
        xn_s[w][l]      = xr0;
        xn_s[w][l + 64] = xr1;
    }
    __syncthreads();

    // P2: hid partials (Wo1 fp32 for FIN, bf16 for DISC)
    {
        const int q = t >> 7, h = t & 127;
        float p0 = 0.f, p1 = 0.f, p2 = 0.f;
#pragma unroll
        for (int kk = 0; kk < 32; ++kk) {
            const int k = q * 32 + kk;
            const float wv = FIN ? Wo1[k * DD + h] : bf2f(wo1b[k * DD + h]);
            p0 = fmaf(xn_s[0][k], wv, p0);
            p1 = fmaf(xn_s[1][k], wv, p1);
            p2 = fmaf(xn_s[2][k], wv, p2);
        }
        part_s[q][0][h] = p0; part_s[q][1][h] = p1; part_s[q][2][h] = p2;
    }
    __syncthreads();

    // P3: hid + logits + [FIN store | softmax + x update]
    if (w < 3) {
        const int row_u = row0 + 32 * w;
        const float hid0 = fmaxf(part_s[0][w][l] + part_s[1][w][l]
                               + part_s[2][w][l] + part_s[3][w][l] + bo1[l], 0.f);
        const float hid1 = fmaxf(part_s[0][w][l + 64] + part_s[1][w][l + 64]
                               + part_s[2][w][l + 64] + part_s[3][w][l + 64] + bo1[l + 64], 0.f);
        float lgp[NCLS];
#pragma unroll
        for (int c = 0; c < NCLS; ++c)
            lgp[c] = hid0 * Wo2[l * NCLS + c] + hid1 * Wo2[(l + 64) * NCLS + c];
#pragma unroll
        for (int s = 1; s < 64; s <<= 1) {
#pragma unroll
            for (int c = 0; c < NCLS; ++c) lgp[c] += __shfl_xor(lgp[c], s);
        }
        if (FIN) {
#pragma unroll
            for (int c = 0; c < NCLS; ++c) {
                if (l == c) {
                    x_all[row_u * NCLS + c] = lgp[c];
                    if (is == 0 && w == 0) out[b * NCLS + c] = lgp[c];
                }
            }
        } else {
            float mx = -1e30f;
#pragma unroll
            for (int c = 0; c < NCLS; ++c) mx = fmaxf(mx, lgp[c]);
            const float inv_tau = 1.f / scalar_as_float(tau_p[0]);
            float p[NCLS], den = 0.f;
#pragma unroll
            for (int c = 0; c < NCLS; ++c) { p[c] = expf((lgp[c] - mx) * inv_tau); den += p[c]; }
            const float invden = 1.f / den;
#pragma unroll
            for (int c = 0; c < NCLS; ++c) {
                const float pc = p[c] * invden;
                xr0 = fmaf(pc, embed_W[(4 + c) * DD + l], xr0);
                xr1 = fmaf(pc, embed_W[(4 + c) * DD + l + 64], xr1);
            }
            x[row_u * DD + l]      = xr0;
            x[row_u * DD + l + 64] = xr1;
            xn_s[w][l]      = xr0;
            xn_s[w][l + 64] = xr1;
        }
    }
    if (FIN) return;
    __syncthreads();

    // P5: next-round xj partials (W1x bf16)
    {
        const int q = t >> 7, h = t & 127;
        float p0 = 0.f, p1 = 0.f, p2 = 0.f;
#pragma unroll
        for (int kk = 0; kk < 32; ++kk) {
            const int k = q * 32 + kk;
            const float wv = bf2f(w1xb[k * DD + h]);
            p0 = fmaf(xn_s[0][k], wv, p0);
            p1 = fmaf(xn_s[1][k], wv, p1);
            p2 = fmaf(xn_s[2][k], wv, p2);
        }
        part_s[q][0][h] = p0; part_s[q][1][h] = p1; part_s[q][2][h] = p2;
    }
    __syncthreads();

    // P6: gather + store xj bf16
    if (w < 3) {
        const int row_u = row0 + 32 * w;
        xj_out[row_u * DD + l] =
            f2bf_fast(part_s[0][w][l] + part_s[1][w][l] + part_s[2][w][l] + part_s[3][w][l]);
        xj_out[row_u * DD + l + 64] =
            f2bf_fast(part_s[0][w][l + 64] + part_s[1][w][l + 64]
                    + part_s[2][w][l + 64] + part_s[3][w][l + 64]);
    }
}

extern "C" void kernel_launch(void* const* d_in, const int* in_sizes, int n_in,
                              void* d_out, int out_size, void* d_ws, size_t ws_size,
                              hipStream_t stream)
{
    (void)in_sizes; (void)n_in; (void)out_size; (void)ws_size;
    const int*   tok     = (const int*)d_in[0];
    const float* Aab     = (const float*)d_in[1];
    const float* embed_W = (const float*)d_in[2];
    const float* W1      = (const float*)d_in[3];
    const float* b1      = (const float*)d_in[4];
    const float* W2      = (const float*)d_in[5];
    const float* b2      = (const float*)d_in[6];
    const float* Wo1     = (const float*)d_in[7];
    const float* bo1     = (const float*)d_in[8];
    const float* Wo2     = (const float*)d_in[9];
    const int*   tau_p   = (const int*)d_in[11];

    float* out   = (float*)d_out;
    float* x_all = out + BB * NCLS;

    float* ws     = (float*)d_ws;
    float* x      = ws;                                    // 196608 f
    float* ATr    = ws + BB * NN * DD;                     // 147456 f
    float* Mtab   = ATr + BB * NN * NN;                    // 25088 f
    float* t2tab  = Mtab + NTOK * NTOK * DD;               // 1792 f
    unsigned short* xjA  = (unsigned short*)(t2tab + NTOK * DD);
    unsigned short* xjB  = xjA + BB * NN * DD;             // 196608 u16 each
    unsigned short* w2hi = xjB + BB * NN * DD;             // 16384 u16
    unsigned short* w1xb = w2hi + DD * DD;                 // 16384 u16
    unsigned short* wo1b = w1xb + DD * DD;                 // 16384 u16

    k_prep<<<228, 256, 0, stream>>>(Aab, embed_W, W1, b1, W2, b2, Wo1,
                                    Mtab, t2tab, ATr, w2hi, w1xb, wo1b);
    k_round0<<<512, 512, 0, stream>>>(tok, ATr, Mtab, embed_W, wo1b, bo1,
                                      Wo2, w1xb, tau_p, x, xjA);
    for (int r = 1; r < 5; ++r) {
        const unsigned short* xin = (r & 1) ? xjA : xjB;
        unsigned short*       xot = (r & 1) ? xjB : xjA;
        if (r < 4)
            k_round<0><<<512, 512, 0, stream>>>(tok, ATr, t2tab, xin, w2hi, b2,
                                                Wo1, wo1b, bo1, Wo2, embed_W, w1xb,
                                                tau_p, x, xot, out, x_all);
        else
            k_round<1><<<512, 512, 0, stream>>>(tok, ATr, t2tab, xin, w2hi, b2,
                                                Wo1, wo1b, bo1, Wo2, embed_W, w1xb,
                                                tau_p, x, xot, out, x_all);
    }
}

// Round 18
// 72.556 us; speedup vs baseline: 1.2217x; 1.0378x over previous
//
#include <hip/hip_runtime.h>
#include <hip/hip_bf16.h>
#include <math.h>

#define BB   16
#define NN   96
#define DD   128
#define NCLS 10
#define NTOK 14

typedef __attribute__((ext_vector_type(8))) short bf16x8;
typedef __attribute__((ext_vector_type(8))) unsigned short u16x8;
typedef __attribute__((ext_vector_type(4))) float f32x4;

__device__ __forceinline__ float scalar_as_float(int v) {
    if (v >= -1000000 && v <= 1000000) return (float)v;
    return __int_as_float(v);
}
// explicit RNE bit-twiddle (cold paths / prep only)
__device__ __forceinline__ unsigned short f2bf(float f) {
    unsigned u = __float_as_uint(f);
    return (unsigned short)((u + 0x7FFFu + ((u >> 16) & 1u)) >> 16);
}
// hot-path RNE convert via native cast (v_cvt_pk_bf16_f32 pairs)
__device__ __forceinline__ unsigned short f2bf_fast(float f) {
    __hip_bfloat16 b = __float2bfloat16(f);
    return *reinterpret_cast<unsigned short*>(&b);
}
__device__ __forceinline__ float bf2f(unsigned short h) {
    return __uint_as_float(((unsigned)h) << 16);
}

#define MFMA(A, B, C) __builtin_amdgcn_mfma_f32_16x16x32_bf16(A, B, C, 0, 0, 0)

// XCD-chunked swizzle (R16: +2.5us): each XCD owns 64 consecutive logical blocks
// = 2 complete batches -> per-XCD L2 xj fill 48 KB instead of 384 KB per round.
__device__ __forceinline__ int swz_bx() {
    const int bxr = blockIdx.x;
    return ((bxr & 7) << 6) | (bxr >> 3);
}

// ---- merged prep ----
__global__ __launch_bounds__(256) void k_prep(
    const float* __restrict__ A, const float* __restrict__ embed_W,
    const float* __restrict__ W1, const float* __restrict__ b1,
    const float* __restrict__ W2, const float* __restrict__ b2,
    const float* __restrict__ Wo1,
    float* __restrict__ Mtab, float* __restrict__ t2tab, float* __restrict__ AT,
    unsigned short* __restrict__ w2hi, unsigned short* __restrict__ w1xb,
    unsigned short* __restrict__ wo1b)
{
    const int bx = blockIdx.x;
    const int t  = threadIdx.x;
    const float* W1x = W1 + DD * DD;

    if (bx < NTOK * NTOK) {        // Mtab(ti,tj): the only 196 distinct H rows in round 0
        const int ti = bx / NTOK, tj = bx % NTOK;
        const int d = t & 127, half = t >> 7;
        __shared__ float part[2][DD];
        __shared__ unsigned short hb[DD];
        {
            const float* erow  = embed_W + (half ? tj : ti) * DD;
            const float* wbase = half ? W1x : W1;
            float acc = 0.f;
#pragma unroll 8
            for (int k = 0; k < DD; ++k)
                acc = fmaf(erow[k], wbase[k * DD + d], acc);
            part[half][d] = acc;
        }
        __syncthreads();
        if (half == 0) {
            const float v = part[0][d] + b1[d];
            if (tj == 0) t2tab[ti * DD + d] = v;
            hb[d] = f2bf(fmaxf(v + part[1][d], 0.f));
        }
        __syncthreads();
        {
            float m = 0.f;
#pragma unroll 8
            for (int kk = 0; kk < 64; ++kk) {
                const int k = half * 64 + kk;
                m = fmaf(bf2f(hb[k]), bf2f(f2bf(W2[k * DD + d])), m);
            }
            part[half][d] = m;
        }
        __syncthreads();
        if (half == 0)
            Mtab[(ti * NTOK + tj) * DD + d] = fmaxf(part[0][d] + part[1][d] + b2[d], 0.f);
    } else if (bx < 212) {         // A transpose
        const int b = bx - 196;
        __shared__ float tile[NN][NN + 1];
        for (int idx = t; idx < NN * NN; idx += 256)
            tile[idx / NN][idx % NN] = A[b * NN * NN + idx];
        __syncthreads();
        for (int idx = t; idx < NN * NN; idx += 256) {
            const int i = idx / NN, j = idx % NN;
            AT[b * NN * NN + idx] = tile[j][i];
        }
    } else if (bx < 220) {         // W2 -> MFMA B-frag layout, bf16
        const int dt = bx - 212;
        const int kc = t >> 6, ll = t & 63;
        const int base = ((dt * 4 + kc) * 64 + ll) * 8;
        const int c = dt * 16 + (ll & 15);
#pragma unroll
        for (int e = 0; e < 8; ++e)
            w2hi[base + e] = f2bf(W2[(kc * 32 + (ll >> 4) * 8 + e) * DD + c]);
    } else if (bx < 224) {         // W1x -> bf16
        const int base = (bx - 220) * 4096 + t * 16;
#pragma unroll
        for (int e = 0; e < 16; ++e) w1xb[base + e] = f2bf(W1x[base + e]);
    } else {                       // Wo1 -> bf16 (DISC rounds only)
        const int base = (bx - 224) * 4096 + t * 16;
#pragma unroll
        for (int e = 0; e < 16; ++e) wo1b[base + e] = f2bf(Wo1[base + e]);
    }
}

// -------- round 0 fast path: agg = A-weighted gather-sum over Mtab --------
__global__ __launch_bounds__(512, 4) void k_round0(
    const int* __restrict__ tok, const float* __restrict__ AT,
    const float* __restrict__ Mtab, const float* __restrict__ embed_W,
    const unsigned short* __restrict__ wo1b, const float* __restrict__ bo1,
    const float* __restrict__ Wo2, const unsigned short* __restrict__ w1xb,
    const int* __restrict__ tau_p,
    float* __restrict__ x, unsigned short* __restrict__ xj_out)
{
    const int bx = swz_bx();
    const int b  = bx >> 5;
    const int is = bx & 31;
    const int t  = threadIdx.x;
    const int w  = t >> 6;
    const int l  = t & 63;
    const int row0 = b * NN + is;

    __shared__ __align__(16) float mt[3][NTOK * DD];
    __shared__ float at3[3][NN];
    __shared__ int   tkj[NN];
    __shared__ float agg_s[3][DD];
    __shared__ float xn_s[3][DD];
    __shared__ float part_s[4][3][DD];

    const int ti0 = tok[row0], ti1 = tok[row0 + 32], ti2 = tok[row0 + 64];
    if (t < NN) {
        tkj[t]    = tok[b * NN + t];
        at3[0][t] = AT[row0 * NN + t];
        at3[1][t] = AT[(row0 + 32) * NN + t];
        at3[2][t] = AT[(row0 + 64) * NN + t];
    }
    for (int idx = t; idx < 3 * NTOK * DD; idx += 512) {
        const int u = idx / (NTOK * DD), rd = idx - u * (NTOK * DD);
        const int tiu = (u == 0) ? ti0 : ((u == 1) ? ti1 : ti2);
        mt[u][rd] = Mtab[tiu * NTOK * DD + rd];
    }
    __syncthreads();

    if (t < 192) {
        const int u = t >> 6, d2 = t & 63;
        const float2* mtu = (const float2*)mt[u];
        float2 acc = {0.f, 0.f};
#pragma unroll 4
        for (int j = 0; j < NN; ++j) {
            const float a = at3[u][j];
            const float2 m = mtu[tkj[j] * 64 + d2];
            acc.x = fmaf(a, m.x, acc.x);
            acc.y = fmaf(a, m.y, acc.y);
        }
        *(float2*)&agg_s[u][d2 * 2] = acc;
    }
    __syncthreads();

    float xr0 = 0.f, xr1 = 0.f;
    if (w < 3) {
        const int tk = (w == 0) ? ti0 : ((w == 1) ? ti1 : ti2);
        xr0 = embed_W[tk * DD + l]      + agg_s[w][l];
        xr1 = embed_W[tk * DD + l + 64] + agg_s[w][l + 64];
        xn_s[w][l]      = xr0;
        xn_s[w][l + 64] = xr1;
    }
    __syncthreads();

    {   // hid partials, Wo1 bf16
        const int q = t >> 7, h = t & 127;
        float p0 = 0.f, p1 = 0.f, p2 = 0.f;
#pragma unroll
        for (int kk = 0; kk < 32; ++kk) {
            const int k = q * 32 + kk;
            const float wv = bf2f(wo1b[k * DD + h]);
            p0 = fmaf(xn_s[0][k], wv, p0);
            p1 = fmaf(xn_s[1][k], wv, p1);
            p2 = fmaf(xn_s[2][k], wv, p2);
        }
        part_s[q][0][h] = p0; part_s[q][1][h] = p1; part_s[q][2][h] = p2;
    }
    __syncthreads();

    if (w < 3) {
        const int row_u = row0 + 32 * w;
        const float hid0 = fmaxf(part_s[0][w][l] + part_s[1][w][l]
                               + part_s[2][w][l] + part_s[3][w][l] + bo1[l], 0.f);
        const float hid1 = fmaxf(part_s[0][w][l + 64] + part_s[1][w][l + 64]
                               + part_s[2][w][l + 64] + part_s[3][w][l + 64] + bo1[l + 64], 0.f);
        float lgp[NCLS];
#pragma unroll
        for (int c = 0; c < NCLS; ++c)
            lgp[c] = hid0 * Wo2[l * NCLS + c] + hid1 * Wo2[(l + 64) * NCLS + c];
#pragma unroll
        for (int s = 1; s < 64; s <<= 1) {
#pragma unroll
            for (int c = 0; c < NCLS; ++c) lgp[c] += __shfl_xor(lgp[c], s);
        }
        float mx = -1e30f;
#pragma unroll
        for (int c = 0; c < NCLS; ++c) mx = fmaxf(mx, lgp[c]);
        const float inv_tau = 1.f / scalar_as_float(tau_p[0]);
        float p[NCLS], den = 0.f;
#pragma unroll
        for (int c = 0; c < NCLS; ++c) { p[c] = expf((lgp[c] - mx) * inv_tau); den += p[c]; }
        const float invden = 1.f / den;
#pragma unroll
        for (int c = 0; c < NCLS; ++c) {
            const float pc = p[c] * invden;
            xr0 = fmaf(pc, embed_W[(4 + c) * DD + l], xr0);
            xr1 = fmaf(pc, embed_W[(4 + c) * DD + l + 64], xr1);
        }
        x[row_u * DD + l]      = xr0;
        x[row_u * DD + l + 64] = xr1;
        xn_s[w][l]      = xr0;
        xn_s[w][l + 64] = xr1;
    }
    __syncthreads();

    {   // next-round xj partials (W1x bf16)
        const int q = t >> 7, h = t & 127;
        float p0 = 0.f, p1 = 0.f, p2 = 0.f;
#pragma unroll
        for (int kk = 0; kk < 32; ++kk) {
            const int k = q * 32 + kk;
            const float wv = bf2f(w1xb[k * DD + h]);
            p0 = fmaf(xn_s[0][k], wv, p0);
            p1 = fmaf(xn_s[1][k], wv, p1);
            p2 = fmaf(xn_s[2][k], wv, p2);
        }
        part_s[q][0][h] = p0; part_s[q][1][h] = p1; part_s[q][2][h] = p2;
    }
    __syncthreads();

    if (w < 3) {
        const int row_u = row0 + 32 * w;
        xj_out[row_u * DD + l] =
            f2bf_fast(part_s[0][w][l] + part_s[1][w][l] + part_s[2][w][l] + part_s[3][w][l]);
        xj_out[row_u * DD + l + 64] =
            f2bf_fast(part_s[0][w][l + 64] + part_s[1][w][l + 64]
                    + part_s[2][w][l + 64] + part_s[3][w][l + 64]);
    }
}

// -------- rounds 1..4: 3-unit pipelined MFMA GEMM + one-wave-per-row epilogue --------
// xj tile register-cached once per block (R14/R15 A/B: -2.2us; all 3 units read
// the same bytes; 12 VGPR, loaded before the pipeline).
template<int FIN>
__global__ __launch_bounds__(512, 4) void k_round(
    const int* __restrict__ tok, const float* __restrict__ AT,
    const float* __restrict__ t2tab,
    const unsigned short* __restrict__ xj_in,
    const unsigned short* __restrict__ w2hi, const float* __restrict__ b2,
    const float* __restrict__ Wo1, const unsigned short* __restrict__ wo1b,
    const float* __restrict__ bo1, const float* __restrict__ Wo2,
    const float* __restrict__ embed_W, const unsigned short* __restrict__ w1xb,
    const int* __restrict__ tau_p,
    float* __restrict__ x, unsigned short* __restrict__ xj_out,
    float* __restrict__ out, float* __restrict__ x_all)
{
    const int bx = swz_bx();
    const int b  = bx >> 5;
    const int is = bx & 31;
    const int t  = threadIdx.x;
    const int w  = t >> 6;
    const int l  = t & 63;
    const int jg  = w >> 2;
    const int dg  = w & 3;
    const int jg3 = jg * 3;
    const int d0 = (t & 15) * 8;
    const int row0 = b * NN + is;

    __shared__ __align__(16) unsigned short hs[2][NN * DD];
    __shared__ float ac_s[2][NN];
    __shared__ float agg_part[3][2][DD];
    __shared__ float xn_s[3][DD];
    __shared__ float part_s[4][3][DD];

    const int tk0 = tok[row0], tk1 = tok[row0 + 32], tk2 = tok[row0 + 64];

    const bf16x8* WH = (const bf16x8*)w2hi;
    const int f0 = (dg * 4) * 64 + l;
    const int f1 = ((dg + 4) * 4) * 64 + l;
    bf16x8 bh00 = WH[f0],        bh10 = WH[f1];
    bf16x8 bh01 = WH[f0 + 64],   bh11 = WH[f1 + 64];
    bf16x8 bh02 = WH[f0 + 128],  bh12 = WH[f1 + 128];
    bf16x8 bh03 = WH[f0 + 192],  bh13 = WH[f1 + 192];
    asm volatile("" : "+v"(bh00), "+v"(bh01), "+v"(bh02), "+v"(bh03),
                      "+v"(bh10), "+v"(bh11), "+v"(bh12), "+v"(bh13));
    const float b2v0 = b2[dg * 16 + (l & 15)];
    const float b2v1 = b2[64 + dg * 16 + (l & 15)];
    const u16x8* xj8 = (const u16x8*)(xj_in + b * NN * DD);

    // xj tile cached in registers once — all 3 units read the same bytes
    const u16x8 xva = xj8[t];
    const u16x8 xvb = xj8[t + 512];
    const u16x8 xvc = xj8[t + 1024];
    const int j_a = t >> 4, j_b = (t + 512) >> 4, j_c = (t + 1024) >> 4;

    auto STAGE = [&](int u, int p) {
        const int row_u = row0 + 32 * u;
        const int tk = (u == 0) ? tk0 : ((u == 1) ? tk1 : tk2);
        const float4 ea = *(const float4*)(t2tab + tk * DD + d0);
        const float4 eb = *(const float4*)(t2tab + tk * DD + d0 + 4);
        float v8[8];
        v8[0] = ea.x; v8[1] = ea.y; v8[2] = ea.z; v8[3] = ea.w;
        v8[4] = eb.x; v8[5] = eb.y; v8[6] = eb.z; v8[7] = eb.w;
        if (t < NN) ac_s[p][t] = AT[row_u * NN + t];
        u16x8 hh;
#pragma unroll
        for (int e = 0; e < 8; ++e) hh[e] = f2bf_fast(fmaxf(bf2f(xva[e]) + v8[e], 0.f));
        *(u16x8*)&hs[p][(j_a * DD + d0) ^ ((j_a & 7) << 3)] = hh;
#pragma unroll
        for (int e = 0; e < 8; ++e) hh[e] = f2bf_fast(fmaxf(bf2f(xvb[e]) + v8[e], 0.f));
        *(u16x8*)&hs[p][(j_b * DD + d0) ^ ((j_b & 7) << 3)] = hh;
#pragma unroll
        for (int e = 0; e < 8; ++e) hh[e] = f2bf_fast(fmaxf(bf2f(xvc[e]) + v8[e], 0.f));
        *(u16x8*)&hs[p][(j_c * DD + d0) ^ ((j_c & 7) << 3)] = hh;
    };

    auto GEMM = [&](int u, int p) {
        float aggp0 = 0.f, aggp1 = 0.f;
        const unsigned short* hb = hs[p];
#pragma unroll
        for (int jj = 0; jj < 3; ++jj) {
            const int jt  = jg3 + jj;
            const int r16 = jt * 16 + (l & 15);
            const int ko  = (l >> 4) * 8;
            const int sw  = (r16 & 7) << 3;
            const bf16x8 a0 = *(const bf16x8*)&hb[(r16 * DD + ko     ) ^ sw];
            const bf16x8 a1 = *(const bf16x8*)&hb[(r16 * DD + ko + 32) ^ sw];
            const bf16x8 a2 = *(const bf16x8*)&hb[(r16 * DD + ko + 64) ^ sw];
            const bf16x8 a3 = *(const bf16x8*)&hb[(r16 * DD + ko + 96) ^ sw];
            f32x4 c0 = {0.f, 0.f, 0.f, 0.f}, c1 = {0.f, 0.f, 0.f, 0.f};
            c0 = MFMA(a0, bh00, c0);  c1 = MFMA(a0, bh10, c1);
            c0 = MFMA(a1, bh01, c0);  c1 = MFMA(a1, bh11, c1);
            c0 = MFMA(a2, bh02, c0);  c1 = MFMA(a2, bh12, c1);
            c0 = MFMA(a3, bh03, c0);  c1 = MFMA(a3, bh13, c1);
#pragma unroll
            for (int r = 0; r < 4; ++r) {
                const float a = ac_s[p][jt * 16 + (l >> 4) * 4 + r];
                aggp0 = fmaf(a, fmaxf(c0[r] + b2v0, 0.f), aggp0);
                aggp1 = fmaf(a, fmaxf(c1[r] + b2v1, 0.f), aggp1);
            }
        }
        aggp0 += __shfl_xor(aggp0, 16); aggp0 += __shfl_xor(aggp0, 32);
        aggp1 += __shfl_xor(aggp1, 16); aggp1 += __shfl_xor(aggp1, 32);
        if (l < 16) {
            agg_part[u][jg][dg * 16 + l]      = aggp0;
            agg_part[u][jg][64 + dg * 16 + l] = aggp1;
        }
    };

    STAGE(0, 0);
    __syncthreads();
    STAGE(1, 1);
    GEMM(0, 0);
    __syncthreads();
    STAGE(2, 0);
    GEMM(1, 1);
    __syncthreads();
    GEMM(2, 0);
    __syncthreads();

    // P1: x update
    float xr0 = 0.f, xr1 = 0.f;
    if (w < 3) {
        const int row_u = row0 + 32 * w;
        xr0 = x[row_u * DD + l]      + agg_part[w][0][l]      + agg_part[w][1][l];
        xr1 = x[row_u * DD + l + 64] + agg_part[w][0][l + 64] + agg_part[w][1][l + 64];
        xn_s[w][l]      = xr0;
        xn_s[w][l + 64] = xr1;
    }
    __syncthreads();

    // P2: hid partials (Wo1 fp32 for FIN, bf16 for DISC)
    {
        const int q = t >> 7, h = t & 127;
        float p0 = 0.f, p1 = 0.f, p2 = 0.f;
#pragma unroll
        for (int kk = 0; kk < 32; ++kk) {
            const int k = q * 32 + kk;
            const float wv = FIN ? Wo1[k * DD + h] : bf2f(wo1b[k * DD + h]);
            p0 = fmaf(xn_s[0][k], wv, p0);
            p1 = fmaf(xn_s[1][k], wv, p1);
            p2 = fmaf(xn_s[2][k], wv, p2);
        }
        part_s[q][0][h] = p0; part_s[q][1][h] = p1; part_s[q][2][h] = p2;
    }
    __syncthreads();

    // P3: hid + logits + [FIN store | softmax + x update]
    if (w < 3) {
        const int row_u = row0 + 32 * w;
        const float hid0 = fmaxf(part_s[0][w][l] + part_s[1][w][l]
                               + part_s[2][w][l] + part_s[3][w][l] + bo1[l], 0.f);
        const float hid1 = fmaxf(part_s[0][w][l + 64] + part_s[1][w][l + 64]
                               + part_s[2][w][l + 64] + part_s[3][w][l + 64] + bo1[l + 64], 0.f);
        float lgp[NCLS];
#pragma unroll
        for (int c = 0; c < NCLS; ++c)
            lgp[c] = hid0 * Wo2[l * NCLS + c] + hid1 * Wo2[(l + 64) * NCLS + c];
#pragma unroll
        for (int s = 1; s < 64; s <<= 1) {
#pragma unroll
            for (int c = 0; c < NCLS; ++c) lgp[c] += __shfl_xor(lgp[c], s);
        }
        if (FIN) {
#pragma unroll
            for (int c = 0; c < NCLS; ++c) {
                if (l == c) {
                    x_all[row_u * NCLS + c] = lgp[c];
                    if (is == 0 && w == 0) out[b * NCLS + c] = lgp[c];
                }
            }
        } else {
            float mx = -1e30f;
#pragma unroll
            for (int c = 0; c < NCLS; ++c) mx = fmaxf(mx, lgp[c]);
            const float inv_tau = 1.f / scalar_as_float(tau_p[0]);
            float p[NCLS], den = 0.f;
#pragma unroll
            for (int c = 0; c < NCLS; ++c) { p[c] = expf((lgp[c] - mx) * inv_tau); den += p[c]; }
            const float invden = 1.f / den;
#pragma unroll
            for (int c = 0; c < NCLS; ++c) {
                const float pc = p[c] * invden;
                xr0 = fmaf(pc, embed_W[(4 + c) * DD + l], xr0);
                xr1 = fmaf(pc, embed_W[(4 + c) * DD + l + 64], xr1);
            }
            x[row_u * DD + l]      = xr0;
            x[row_u * DD + l + 64] = xr1;
            xn_s[w][l]      = xr0;
            xn_s[w][l + 64] = xr1;
        }
    }
    if (FIN) return;
    __syncthreads();

    // P5: next-round xj partials (W1x bf16)
    {
        const int q = t >> 7, h = t & 127;
        float p0 = 0.f, p1 = 0.f, p2 = 0.f;
#pragma unroll
        for (int kk = 0; kk < 32; ++kk) {
            const int k = q * 32 + kk;
            const float wv = bf2f(w1xb[k * DD + h]);
            p0 = fmaf(xn_s[0][k], wv, p0);
            p1 = fmaf(xn_s[1][k], wv, p1);
            p2 = fmaf(xn_s[2][k], wv, p2);
        }
        part_s[q][0][h] = p0; part_s[q][1][h] = p1; part_s[q][2][h] = p2;
    }
    __syncthreads();

    // P6: gather + store xj bf16
    if (w < 3) {
        const int row_u = row0 + 32 * w;
        xj_out[row_u * DD + l] =
            f2bf_fast(part_s[0][w][l] + part_s[1][w][l] + part_s[2][w][l] + part_s[3][w][l]);
        xj_out[row_u * DD + l + 64] =
            f2bf_fast(part_s[0][w][l + 64] + part_s[1][w][l + 64]
                    + part_s[2][w][l + 64] + part_s[3][w][l + 64]);
    }
}

extern "C" void kernel_launch(void* const* d_in, const int* in_sizes, int n_in,
                              void* d_out, int out_size, void* d_ws, size_t ws_size,
                              hipStream_t stream)
{
    (void)in_sizes; (void)n_in; (void)out_size; (void)ws_size;
    const int*   tok     = (const int*)d_in[0];
    const float* Aab     = (const float*)d_in[1];
    const float* embed_W = (const float*)d_in[2];
    const float* W1      = (const float*)d_in[3];
    const float* b1      = (const float*)d_in[4];
    const float* W2      = (const float*)d_in[5];
    const float* b2      = (const float*)d_in[6];
    const float* Wo1     = (const float*)d_in[7];
    const float* bo1     = (const float*)d_in[8];
    const float* Wo2     = (const float*)d_in[9];
    const int*   tau_p   = (const int*)d_in[11];

    float* out   = (float*)d_out;
    float* x_all = out + BB * NCLS;

    float* ws     = (float*)d_ws;
    float* x      = ws;                                    // 196608 f
    float* ATr    = ws + BB * NN * DD;                     // 147456 f
    float* Mtab   = ATr + BB * NN * NN;                    // 25088 f
    float* t2tab  = Mtab + NTOK * NTOK * DD;               // 1792 f
    unsigned short* xjA  = (unsigned short*)(t2tab + NTOK * DD);
    unsigned short* xjB  = xjA + BB * NN * DD;             // 196608 u16 each
    unsigned short* w2hi = xjB + BB * NN * DD;             // 16384 u16
    unsigned short* w1xb = w2hi + DD * DD;                 // 16384 u16
    unsigned short* wo1b = w1xb + DD * DD;                 // 16384 u16

    k_prep<<<228, 256, 0, stream>>>(Aab, embed_W, W1, b1, W2, b2, Wo1,
                                    Mtab, t2tab, ATr, w2hi, w1xb, wo1b);
    k_round0<<<512, 512, 0, stream>>>(tok, ATr, Mtab, embed_W, wo1b, bo1,
                                      Wo2, w1xb, tau_p, x, xjA);
    for (int r = 1; r < 5; ++r) {
        const unsigned short* xin = (r & 1) ? xjA : xjB;
        unsigned short*       xot = (r & 1) ? xjB : xjA;
        if (r < 4)
            k_round<0><<<512, 512, 0, stream>>>(tok, ATr, t2tab, xin, w2hi, b2,
                                                Wo1, wo1b, bo1, Wo2, embed_W, w1xb,
                                                tau_p, x, xot, out, x_all);
        else
            k_round<1><<<512, 512, 0, stream>>>(tok, ATr, t2tab, xin, w2hi, b2,
                                                Wo1, wo1b, bo1, Wo2, embed_W, w1xb,
                                                tau_p, x, xot, out, x_all);
    }
}

// Round 19
// 71.919 us; speedup vs baseline: 1.2325x; 1.0089x over previous
//
#include <hip/hip_runtime.h>
#include <hip/hip_bf16.h>
#include <math.h>

#define BB   16
#define NN   96
#define DD   128
#define NCLS 10
#define NTOK 14

typedef __attribute__((ext_vector_type(8))) short bf16x8;
typedef __attribute__((ext_vector_type(8))) unsigned short u16x8;
typedef __attribute__((ext_vector_type(4))) float f32x4;

__device__ __forceinline__ float scalar_as_float(int v) {
    if (v >= -1000000 && v <= 1000000) return (float)v;
    return __int_as_float(v);
}
// explicit RNE bit-twiddle (cold paths / prep only)
__device__ __forceinline__ unsigned short f2bf(float f) {
    unsigned u = __float_as_uint(f);
    return (unsigned short)((u + 0x7FFFu + ((u >> 16) & 1u)) >> 16);
}
// hot-path RNE convert via native cast (v_cvt_pk_bf16_f32 pairs)
__device__ __forceinline__ unsigned short f2bf_fast(float f) {
    __hip_bfloat16 b = __float2bfloat16(f);
    return *reinterpret_cast<unsigned short*>(&b);
}
__device__ __forceinline__ float bf2f(unsigned short h) {
    return __uint_as_float(((unsigned)h) << 16);
}

#define MFMA(A, B, C) __builtin_amdgcn_mfma_f32_16x16x32_bf16(A, B, C, 0, 0, 0)

// XCD-chunked swizzle (R16: +2.5us)
__device__ __forceinline__ int swz_bx() {
    const int bxr = blockIdx.x;
    return ((bxr & 7) << 6) | (bxr >> 3);
}

// ---- merged prep ----
__global__ __launch_bounds__(256) void k_prep(
    const float* __restrict__ A, const float* __restrict__ embed_W,
    const float* __restrict__ W1, const float* __restrict__ b1,
    const float* __restrict__ W2, const float* __restrict__ b2,
    const float* __restrict__ Wo1,
    float* __restrict__ Mtab, float* __restrict__ t2tab, float* __restrict__ AT,
    unsigned short* __restrict__ w2hi, unsigned short* __restrict__ w1xb,
    unsigned short* __restrict__ wo1b)
{
    const int bx = blockIdx.x;
    const int t  = threadIdx.x;
    const float* W1x = W1 + DD * DD;

    if (bx < NTOK * NTOK) {        // Mtab(ti,tj): the only 196 distinct H rows in round 0
        const int ti = bx / NTOK, tj = bx % NTOK;
        const int d = t & 127, half = t >> 7;
        __shared__ float part[2][DD];
        __shared__ unsigned short hb[DD];
        {
            const float* erow  = embed_W + (half ? tj : ti) * DD;
            const float* wbase = half ? W1x : W1;
            float acc = 0.f;
#pragma unroll 8
            for (int k = 0; k < DD; ++k)
                acc = fmaf(erow[k], wbase[k * DD + d], acc);
            part[half][d] = acc;
        }
        __syncthreads();
        if (half == 0) {
            const float v = part[0][d] + b1[d];
            if (tj == 0) t2tab[ti * DD + d] = v;
            hb[d] = f2bf(fmaxf(v + part[1][d], 0.f));
        }
        __syncthreads();
        {
            float m = 0.f;
#pragma unroll 8
            for (int kk = 0; kk < 64; ++kk) {
                const int k = half * 64 + kk;
                m = fmaf(bf2f(hb[k]), bf2f(f2bf(W2[k * DD + d])), m);
            }
            part[half][d] = m;
        }
        __syncthreads();
        if (half == 0)
            Mtab[(ti * NTOK + tj) * DD + d] = fmaxf(part[0][d] + part[1][d] + b2[d], 0.f);
    } else if (bx < 212) {         // A transpose
        const int b = bx - 196;
        __shared__ float tile[NN][NN + 1];
        for (int idx = t; idx < NN * NN; idx += 256)
            tile[idx / NN][idx % NN] = A[b * NN * NN + idx];
        __syncthreads();
        for (int idx = t; idx < NN * NN; idx += 256) {
            const int i = idx / NN, j = idx % NN;
            AT[b * NN * NN + idx] = tile[j][i];
        }
    } else if (bx < 220) {         // W2 -> MFMA B-frag layout, bf16
        const int dt = bx - 212;
        const int kc = t >> 6, ll = t & 63;
        const int base = ((dt * 4 + kc) * 64 + ll) * 8;
        const int c = dt * 16 + (ll & 15);
#pragma unroll
        for (int e = 0; e < 8; ++e)
            w2hi[base + e] = f2bf(W2[(kc * 32 + (ll >> 4) * 8 + e) * DD + c]);
    } else if (bx < 224) {         // W1x -> bf16
        const int base = (bx - 220) * 4096 + t * 16;
#pragma unroll
        for (int e = 0; e < 16; ++e) w1xb[base + e] = f2bf(W1x[base + e]);
    } else {                       // Wo1 -> bf16 (DISC rounds only)
        const int base = (bx - 224) * 4096 + t * 16;
#pragma unroll
        for (int e = 0; e < 16; ++e) wo1b[base + e] = f2bf(Wo1[base + e]);
    }
}

// -------- round 0 fast path: agg = A-weighted gather-sum over Mtab --------
__global__ __launch_bounds__(512, 4) void k_round0(
    const int* __restrict__ tok, const float* __restrict__ AT,
    const float* __restrict__ Mtab, const float* __restrict__ embed_W,
    const unsigned short* __restrict__ wo1b, const float* __restrict__ bo1,
    const float* __restrict__ Wo2, const unsigned short* __restrict__ w1xb,
    const int* __restrict__ tau_p,
    float* __restrict__ x, unsigned short* __restrict__ xj_out)
{
    const int bx = swz_bx();
    const int b  = bx >> 5;
    const int is = bx & 31;
    const int t  = threadIdx.x;
    const int w  = t >> 6;
    const int l  = t & 63;
    const int row0 = b * NN + is;

    __shared__ __align__(16) float mt[3][NTOK * DD];
    __shared__ float at3[3][NN];
    __shared__ int   tkj[NN];
    __shared__ float agg_s[3][DD];
    __shared__ float xn_s[3][DD];
    __shared__ float part_s[4][3][DD];

    const int ti0 = tok[row0], ti1 = tok[row0 + 32], ti2 = tok[row0 + 64];
    if (t < NN) {
        tkj[t]    = tok[b * NN + t];
        at3[0][t] = AT[row0 * NN + t];
        at3[1][t] = AT[(row0 + 32) * NN + t];
        at3[2][t] = AT[(row0 + 64) * NN + t];
    }
    for (int idx = t; idx < 3 * NTOK * DD; idx += 512) {
        const int u = idx / (NTOK * DD), rd = idx - u * (NTOK * DD);
        const int tiu = (u == 0) ? ti0 : ((u == 1) ? ti1 : ti2);
        mt[u][rd] = Mtab[tiu * NTOK * DD + rd];
    }
    __syncthreads();

    if (t < 192) {
        const int u = t >> 6, d2 = t & 63;
        const float2* mtu = (const float2*)mt[u];
        float2 acc = {0.f, 0.f};
#pragma unroll 4
        for (int j = 0; j < NN; ++j) {
            const float a = at3[u][j];
            const float2 m = mtu[tkj[j] * 64 + d2];
            acc.x = fmaf(a, m.x, acc.x);
            acc.y = fmaf(a, m.y, acc.y);
        }
        *(float2*)&agg_s[u][d2 * 2] = acc;
    }
    __syncthreads();

    float xr0 = 0.f, xr1 = 0.f;
    if (w < 3) {
        const int tk = (w == 0) ? ti0 : ((w == 1) ? ti1 : ti2);
        xr0 = embed_W[tk * DD + l]      + agg_s[w][l];
        xr1 = embed_W[tk * DD + l + 64] + agg_s[w][l + 64];
        xn_s[w][l]      = xr0;
        xn_s[w][l + 64] = xr1;
    }
    __syncthreads();

    {   // hid partials, Wo1 bf16
        const int q = t >> 7, h = t & 127;
        float p0 = 0.f, p1 = 0.f, p2 = 0.f;
#pragma unroll
        for (int kk = 0; kk < 32; ++kk) {
            const int k = q * 32 + kk;
            const float wv = bf2f(wo1b[k * DD + h]);
            p0 = fmaf(xn_s[0][k], wv, p0);
            p1 = fmaf(xn_s[1][k], wv, p1);
            p2 = fmaf(xn_s[2][k], wv, p2);
        }
        part_s[q][0][h] = p0; part_s[q][1][h] = p1; part_s[q][2][h] = p2;
    }
    __syncthreads();

    if (w < 3) {
        const int row_u = row0 + 32 * w;
        const float hid0 = fmaxf(part_s[0][w][l] + part_s[1][w][l]
                               + part_s[2][w][l] + part_s[3][w][l] + bo1[l], 0.f);
        const float hid1 = fmaxf(part_s[0][w][l + 64] + part_s[1][w][l + 64]
                               + part_s[2][w][l + 64] + part_s[3][w][l + 64] + bo1[l + 64], 0.f);
        float lgp[NCLS];
#pragma unroll
        for (int c = 0; c < NCLS; ++c)
            lgp[c] = hid0 * Wo2[l * NCLS + c] + hid1 * Wo2[(l + 64) * NCLS + c];
#pragma unroll
        for (int s = 1; s < 64; s <<= 1) {
#pragma unroll
            for (int c = 0; c < NCLS; ++c) lgp[c] += __shfl_xor(lgp[c], s);
        }
        float mx = -1e30f;
#pragma unroll
        for (int c = 0; c < NCLS; ++c) mx = fmaxf(mx, lgp[c]);
        const float inv_tau = 1.f / scalar_as_float(tau_p[0]);
        float p[NCLS], den = 0.f;
#pragma unroll
        for (int c = 0; c < NCLS; ++c) { p[c] = expf((lgp[c] - mx) * inv_tau); den += p[c]; }
        const float invden = 1.f / den;
#pragma unroll
        for (int c = 0; c < NCLS; ++c) {
            const float pc = p[c] * invden;
            xr0 = fmaf(pc, embed_W[(4 + c) * DD + l], xr0);
            xr1 = fmaf(pc, embed_W[(4 + c) * DD + l + 64], xr1);
        }
        x[row_u * DD + l]      = xr0;
        x[row_u * DD + l + 64] = xr1;
        xn_s[w][l]      = xr0;
        xn_s[w][l + 64] = xr1;
    }
    __syncthreads();

    {   // next-round xj partials (W1x bf16)
        const int q = t >> 7, h = t & 127;
        float p0 = 0.f, p1 = 0.f, p2 = 0.f;
#pragma unroll
        for (int kk = 0; kk < 32; ++kk) {
            const int k = q * 32 + kk;
            const float wv = bf2f(w1xb[k * DD + h]);
            p0 = fmaf(xn_s[0][k], wv, p0);
            p1 = fmaf(xn_s[1][k], wv, p1);
            p2 = fmaf(xn_s[2][k], wv, p2);
        }
        part_s[q][0][h] = p0; part_s[q][1][h] = p1; part_s[q][2][h] = p2;
    }
    __syncthreads();

    if (w < 3) {
        const int row_u = row0 + 32 * w;
        xj_out[row_u * DD + l] =
            f2bf_fast(part_s[0][w][l] + part_s[1][w][l] + part_s[2][w][l] + part_s[3][w][l]);
        xj_out[row_u * DD + l + 64] =
            f2bf_fast(part_s[0][w][l + 64] + part_s[1][w][l + 64]
                    + part_s[2][w][l + 64] + part_s[3][w][l + 64]);
    }
}

// -------- rounds 1..4: 3-unit pipelined MFMA GEMM + one-wave-per-row epilogue --------
// R19: ac_s[3][NN] + x-row preloaded at kernel start (off the barrier critical path);
// xj tile register-cached (R18); all numerics unchanged.
template<int FIN>
__global__ __launch_bounds__(512, 4) void k_round(
    const int* __restrict__ tok, const float* __restrict__ AT,
    const float* __restrict__ t2tab,
    const unsigned short* __restrict__ xj_in,
    const unsigned short* __restrict__ w2hi, const float* __restrict__ b2,
    const float* __restrict__ Wo1, const unsigned short* __restrict__ wo1b,
    const float* __restrict__ bo1, const float* __restrict__ Wo2,
    const float* __restrict__ embed_W, const unsigned short* __restrict__ w1xb,
    const int* __restrict__ tau_p,
    float* __restrict__ x, unsigned short* __restrict__ xj_out,
    float* __restrict__ out, float* __restrict__ x_all)
{
    const int bx = swz_bx();
    const int b  = bx >> 5;
    const int is = bx & 31;
    const int t  = threadIdx.x;
    const int w  = t >> 6;
    const int l  = t & 63;
    const int jg  = w >> 2;
    const int dg  = w & 3;
    const int jg3 = jg * 3;
    const int d0 = (t & 15) * 8;
    const int row0 = b * NN + is;

    __shared__ __align__(16) unsigned short hs[2][NN * DD];
    __shared__ float ac_s[3][NN];
    __shared__ float agg_part[3][2][DD];
    __shared__ float xn_s[3][DD];
    __shared__ float part_s[4][3][DD];

    const int tk0 = tok[row0], tk1 = tok[row0 + 32], tk2 = tok[row0 + 64];

    // preload all 3 A-columns (off STAGE's critical path; written before first barrier)
    if (t < NN) {
        ac_s[0][t] = AT[row0 * NN + t];
        ac_s[1][t] = AT[(row0 + 32) * NN + t];
        ac_s[2][t] = AT[(row0 + 64) * NN + t];
    }
    // preload this block's x row (block-private; hides L2 latency under the pipeline)
    float xr0 = 0.f, xr1 = 0.f;
    if (w < 3) {
        const int row_u = row0 + 32 * w;
        xr0 = x[row_u * DD + l];
        xr1 = x[row_u * DD + l + 64];
    }

    const bf16x8* WH = (const bf16x8*)w2hi;
    const int f0 = (dg * 4) * 64 + l;
    const int f1 = ((dg + 4) * 4) * 64 + l;
    bf16x8 bh00 = WH[f0],        bh10 = WH[f1];
    bf16x8 bh01 = WH[f0 + 64],   bh11 = WH[f1 + 64];
    bf16x8 bh02 = WH[f0 + 128],  bh12 = WH[f1 + 128];
    bf16x8 bh03 = WH[f0 + 192],  bh13 = WH[f1 + 192];
    asm volatile("" : "+v"(bh00), "+v"(bh01), "+v"(bh02), "+v"(bh03),
                      "+v"(bh10), "+v"(bh11), "+v"(bh12), "+v"(bh13));
    const float b2v0 = b2[dg * 16 + (l & 15)];
    const float b2v1 = b2[64 + dg * 16 + (l & 15)];
    const u16x8* xj8 = (const u16x8*)(xj_in + b * NN * DD);

    // xj tile cached in registers once — all 3 units read the same bytes
    const u16x8 xva = xj8[t];
    const u16x8 xvb = xj8[t + 512];
    const u16x8 xvc = xj8[t + 1024];
    const int j_a = t >> 4, j_b = (t + 512) >> 4, j_c = (t + 1024) >> 4;

    auto STAGE = [&](int u, int p) {
        const int tk = (u == 0) ? tk0 : ((u == 1) ? tk1 : tk2);
        const float4 ea = *(const float4*)(t2tab + tk * DD + d0);
        const float4 eb = *(const float4*)(t2tab + tk * DD + d0 + 4);
        float v8[8];
        v8[0] = ea.x; v8[1] = ea.y; v8[2] = ea.z; v8[3] = ea.w;
        v8[4] = eb.x; v8[5] = eb.y; v8[6] = eb.z; v8[7] = eb.w;
        u16x8 hh;
#pragma unroll
        for (int e = 0; e < 8; ++e) hh[e] = f2bf_fast(fmaxf(bf2f(xva[e]) + v8[e], 0.f));
        *(u16x8*)&hs[p][(j_a * DD + d0) ^ ((j_a & 7) << 3)] = hh;
#pragma unroll
        for (int e = 0; e < 8; ++e) hh[e] = f2bf_fast(fmaxf(bf2f(xvb[e]) + v8[e], 0.f));
        *(u16x8*)&hs[p][(j_b * DD + d0) ^ ((j_b & 7) << 3)] = hh;
#pragma unroll
        for (int e = 0; e < 8; ++e) hh[e] = f2bf_fast(fmaxf(bf2f(xvc[e]) + v8[e], 0.f));
        *(u16x8*)&hs[p][(j_c * DD + d0) ^ ((j_c & 7) << 3)] = hh;
    };

    auto GEMM = [&](int u, int p) {
        float aggp0 = 0.f, aggp1 = 0.f;
        const unsigned short* hb = hs[p];
#pragma unroll
        for (int jj = 0; jj < 3; ++jj) {
            const int jt  = jg3 + jj;
            const int r16 = jt * 16 + (l & 15);
            const int ko  = (l >> 4) * 8;
            const int sw  = (r16 & 7) << 3;
            const bf16x8 a0 = *(const bf16x8*)&hb[(r16 * DD + ko     ) ^ sw];
            const bf16x8 a1 = *(const bf16x8*)&hb[(r16 * DD + ko + 32) ^ sw];
            const bf16x8 a2 = *(const bf16x8*)&hb[(r16 * DD + ko + 64) ^ sw];
            const bf16x8 a3 = *(const bf16x8*)&hb[(r16 * DD + ko + 96) ^ sw];
            f32x4 c0 = {0.f, 0.f, 0.f, 0.f}, c1 = {0.f, 0.f, 0.f, 0.f};
            c0 = MFMA(a0, bh00, c0);  c1 = MFMA(a0, bh10, c1);
            c0 = MFMA(a1, bh01, c0);  c1 = MFMA(a1, bh11, c1);
            c0 = MFMA(a2, bh02, c0);  c1 = MFMA(a2, bh12, c1);
            c0 = MFMA(a3, bh03, c0);  c1 = MFMA(a3, bh13, c1);
#pragma unroll
            for (int r = 0; r < 4; ++r) {
                const float a = ac_s[u][jt * 16 + (l >> 4) * 4 + r];
                aggp0 = fmaf(a, fmaxf(c0[r] + b2v0, 0.f), aggp0);
                aggp1 = fmaf(a, fmaxf(c1[r] + b2v1, 0.f), aggp1);
            }
        }
        aggp0 += __shfl_xor(aggp0, 16); aggp0 += __shfl_xor(aggp0, 32);
        aggp1 += __shfl_xor(aggp1, 16); aggp1 += __shfl_xor(aggp1, 32);
        if (l < 16) {
            agg_part[u][jg][dg * 16 + l]      = aggp0;
            agg_part[u][jg][64 + dg * 16 + l] = aggp1;
        }
    };

    STAGE(0, 0);
    __syncthreads();
    STAGE(1, 1);
    GEMM(0, 0);
    __syncthreads();
    STAGE(2, 0);
    GEMM(1, 1);
    __syncthreads();
    GEMM(2, 0);
    __syncthreads();

    // P1: x update (x row already in registers)
    if (w < 3) {
        xr0 += agg_part[w][0][l]      + agg_part[w][1][l];
        xr1 += agg_part[w][0][l + 64] + agg_part[w][1][l + 64];
        xn_s[w][l]      = xr0;
        xn_s[w][l + 64] = xr1;
    }
    __syncthreads();

    // P2: hid partials (Wo1 fp32 for FIN, bf16 for DISC)
    {
        const int q = t >> 7, h = t & 127;
        float p0 = 0.f, p1 = 0.f, p2 = 0.f;
#pragma unroll
        for (int kk = 0; kk < 32; ++kk) {
            const int k = q * 32 + kk;
            const float wv = FIN ? Wo1[k * DD + h] : bf2f(wo1b[k * DD + h]);
            p0 = fmaf(xn_s[0][k], wv, p0);
            p1 = fmaf(xn_s[1][k], wv, p1);
            p2 = fmaf(xn_s[2][k], wv, p2);
        }
        part_s[q][0][h] = p0; part_s[q][1][h] = p1; part_s[q][2][h] = p2;
    }
    __syncthreads();

    // P3: hid + logits + [FIN store | softmax + x update]
    if (w < 3) {
        const int row_u = row0 + 32 * w;
        const float hid0 = fmaxf(part_s[0][w][l] + part_s[1][w][l]
                               + part_s[2][w][l] + part_s[3][w][l] + bo1[l], 0.f);
        const float hid1 = fmaxf(part_s[0][w][l + 64] + part_s[1][w][l + 64]
                               + part_s[2][w][l + 64] + part_s[3][w][l + 64] + bo1[l + 64], 0.f);
        float lgp[NCLS];
#pragma unroll
        for (int c = 0; c < NCLS; ++c)
            lgp[c] = hid0 * Wo2[l * NCLS + c] + hid1 * Wo2[(l + 64) * NCLS + c];
#pragma unroll
        for (int s = 1; s < 64; s <<= 1) {
#pragma unroll
            for (int c = 0; c < NCLS; ++c) lgp[c] += __shfl_xor(lgp[c], s);
        }
        if (FIN) {
#pragma unroll
            for (int c = 0; c < NCLS; ++c) {
                if (l == c) {
                    x_all[row_u * NCLS + c] = lgp[c];
                    if (is == 0 && w == 0) out[b * NCLS + c] = lgp[c];
                }
            }
        } else {
            float mx = -1e30f;
#pragma unroll
            for (int c = 0; c < NCLS; ++c) mx = fmaxf(mx, lgp[c]);
            const float inv_tau = 1.f / scalar_as_float(tau_p[0]);
            float p[NCLS], den = 0.f;
#pragma unroll
            for (int c = 0; c < NCLS; ++c) { p[c] = expf((lgp[c] - mx) * inv_tau); den += p[c]; }
            const float invden = 1.f / den;
#pragma unroll
            for (int c = 0; c < NCLS; ++c) {
                const float pc = p[c] * invden;
                xr0 = fmaf(pc, embed_W[(4 + c) * DD + l], xr0);
                xr1 = fmaf(pc, embed_W[(4 + c) * DD + l + 64], xr1);
            }
            x[row_u * DD + l]      = xr0;
            x[row_u * DD + l + 64] = xr1;
            xn_s[w][l]      = xr0;
            xn_s[w][l + 64] = xr1;
        }
    }
    if (FIN) return;
    __syncthreads();

    // P5: next-round xj partials (W1x bf16)
    {
        const int q = t >> 7, h = t & 127;
        float p0 = 0.f, p1 = 0.f, p2 = 0.f;
#pragma unroll
        for (int kk = 0; kk < 32; ++kk) {
            const int k = q * 32 + kk;
            const float wv = bf2f(w1xb[k * DD + h]);
            p0 = fmaf(xn_s[0][k], wv, p0);
            p1 = fmaf(xn_s[1][k], wv, p1);
            p2 = fmaf(xn_s[2][k], wv, p2);
        }
        part_s[q][0][h] = p0; part_s[q][1][h] = p1; part_s[q][2][h] = p2;
    }
    __syncthreads();

    // P6: gather + store xj bf16
    if (w < 3) {
        const int row_u = row0 + 32 * w;
        xj_out[row_u * DD + l] =
            f2bf_fast(part_s[0][w][l] + part_s[1][w][l] + part_s[2][w][l] + part_s[3][w][l]);
        xj_out[row_u * DD + l + 64] =
            f2bf_fast(part_s[0][w][l + 64] + part_s[1][w][l + 64]
                    + part_s[2][w][l + 64] + part_s[3][w][l + 64]);
    }
}

extern "C" void kernel_launch(void* const* d_in, const int* in_sizes, int n_in,
                              void* d_out, int out_size, void* d_ws, size_t ws_size,
                              hipStream_t stream)
{
    (void)in_sizes; (void)n_in; (void)out_size; (void)ws_size;
    const int*   tok     = (const int*)d_in[0];
    const float* Aab     = (const float*)d_in[1];
    const float* embed_W = (const float*)d_in[2];
    const float* W1      = (const float*)d_in[3];
    const float* b1      = (const float*)d_in[4];
    const float* W2      = (const float*)d_in[5];
    const float* b2      = (const float*)d_in[6];
    const float* Wo1     = (const float*)d_in[7];
    const float* bo1     = (const float*)d_in[8];
    const float* Wo2     = (const float*)d_in[9];
    const int*   tau_p   = (const int*)d_in[11];

    float* out   = (float*)d_out;
    float* x_all = out + BB * NCLS;

    float* ws     = (float*)d_ws;
    float* x      = ws;                                    // 196608 f
    float* ATr    = ws + BB * NN * DD;                     // 147456 f
    float* Mtab   = ATr + BB * NN * NN;                    // 25088 f
    float* t2tab  = Mtab + NTOK * NTOK * DD;               // 1792 f
    unsigned short* xjA  = (unsigned short*)(t2tab + NTOK * DD);
    unsigned short* xjB  = xjA + BB * NN * DD;             // 196608 u16 each
    unsigned short* w2hi = xjB + BB * NN * DD;             // 16384 u16
    unsigned short* w1xb = w2hi + DD * DD;                 // 16384 u16
    unsigned short* wo1b = w1xb + DD * DD;                 // 16384 u16

    k_prep<<<228, 256, 0, stream>>>(Aab, embed_W, W1, b1, W2, b2, Wo1,
                                    Mtab, t2tab, ATr, w2hi, w1xb, wo1b);
    k_round0<<<512, 512, 0, stream>>>(tok, ATr, Mtab, embed_W, wo1b, bo1,
                                      Wo2, w1xb, tau_p, x, xjA);
    for (int r = 1; r < 5; ++r) {
        const unsigned short* xin = (r & 1) ? xjA : xjB;
        unsigned short*       xot = (r & 1) ? xjB : xjA;
        if (r < 4)
            k_round<0><<<512, 512, 0, stream>>>(tok, ATr, t2tab, xin, w2hi, b2,
                                                Wo1, wo1b, bo1, Wo2, embed_W, w1xb,
                                                tau_p, x, xot, out, x_all);
        else
            k_round<1><<<512, 512, 0, stream>>>(tok, ATr, t2tab, xin, w2hi, b2,
                                                Wo1, wo1b, bo1, Wo2, embed_W, w1xb,
                                                tau_p, x, xot, out, x_all);
    }
}